// Round 5
// baseline (1029.641 us; speedup 1.0000x reference)
//
#include <hip/hip_runtime.h>
#include <math.h>

#define N_NODES 15000
#define N_EDGES 40000
#define N_GRAPHS 750
#define N_TILES 938   // ceil(15000/16)

__device__ __forceinline__ float sigmoidf_(float x) { return 1.f / (1.f + expf(-x)); }

// ---------------- CSR prep ----------------
__global__ void count_kernel(const int* __restrict__ src, const int* __restrict__ dst,
                             int* __restrict__ tcnt, float* __restrict__ deg) {
    int e = blockIdx.x * 256 + threadIdx.x;
    if (e >= N_EDGES) return;
    atomicAdd(&tcnt[src[e] >> 4], 1);
    atomicAdd(&deg[dst[e]], 1.f);
}

__global__ void tscan_kernel(const int* __restrict__ tcnt, int* __restrict__ tptr,
                             int* __restrict__ cursor) {
    __shared__ int buf[1024];
    int t = threadIdx.x;
    int v = (t < N_TILES) ? tcnt[t] : 0;
    buf[t] = v;
    __syncthreads();
    for (int ofs = 1; ofs < 1024; ofs <<= 1) {
        int a = (t >= ofs) ? buf[t - ofs] : 0;
        __syncthreads();
        buf[t] += a;
        __syncthreads();
    }
    if (t < N_TILES) {
        int excl = buf[t] - v;
        tptr[t] = excl;
        cursor[t] = excl;
    }
    if (t == N_TILES - 1) tptr[N_TILES] = buf[t];
}

__global__ void fill_kernel(const int* __restrict__ src, int* __restrict__ cursor,
                            int* __restrict__ edge_list) {
    int e = blockIdx.x * 256 + threadIdx.x;
    if (e >= N_EDGES) return;
    int slot = atomicAdd(&cursor[src[e] >> 4], 1);
    edge_list[slot] = e;
}

// ---------------- fused prep mega-kernel (block-range partitioned) ----------------
// blocks [0,3750): proj + initial Tb (4 nodes each)
// blocks [3750,13750): h1 (4 edges each)
// blocks [13750,14006): pack e2_W
// blocks [14006,14294): transpose recurrent weights
// blocks [14294,14353): gptr
__global__ __launch_bounds__(256)
void prep_kernel(const float* __restrict__ x, const float* __restrict__ in_W,
                 const float* __restrict__ in_b, float* __restrict__ node_h,
                 const float* __restrict__ e2b, float* __restrict__ Tb_g,
                 const float* __restrict__ ea, const float* __restrict__ e1_W,
                 const float* __restrict__ e1_b, float* __restrict__ h1,
                 const float* __restrict__ e2W, float4* __restrict__ Bp4,
                 const float* __restrict__ lWih, const float* __restrict__ lWhh,
                 const float* __restrict__ gWih, const float* __restrict__ gWhh,
                 float* __restrict__ lWihT, float* __restrict__ lWhhT,
                 float* __restrict__ gWihT, float* __restrict__ gWhhT,
                 const int* __restrict__ batch, int* __restrict__ gptr) {
    int b = blockIdx.x;
    int tid = threadIdx.x;
    if (b < 3750) {
        __shared__ float xs[4][32];
        __shared__ float hrow[4][64];
        int n0 = b * 4;
        if (tid < 128) xs[tid >> 5][tid & 31] = x[n0 * 32 + tid];
        __syncthreads();
        int nn = tid >> 6, f = tid & 63;
        float s = in_b[f];
        #pragma unroll
        for (int i = 0; i < 32; ++i) s += xs[nn][i] * in_W[i * 64 + f];
        s = fmaxf(s, 0.f);
        node_h[(size_t)(n0 + nn) * 64 + f] = s;
        hrow[nn][f] = s;
        __syncthreads();
        float t2 = 0.f;
        #pragma unroll 8
        for (int d = 0; d < 64; ++d) t2 += hrow[nn][d] * e2b[d * 64 + f];
        Tb_g[(size_t)(n0 + nn) * 64 + f] = t2;
    } else if (b < 13750) {
        __shared__ float eas[4][16];
        int e0 = (b - 3750) * 4;
        if (tid < 64) eas[tid >> 4][tid & 15] = ea[e0 * 16 + tid];
        __syncthreads();
        int nn = tid >> 6, f = tid & 63;
        float s = e1_b[f];
        #pragma unroll
        for (int i = 0; i < 16; ++i) s += eas[nn][i] * e1_W[i * 64 + f];
        h1[(size_t)(e0 + nn) * 64 + f] = fmaxf(s, 0.f);
    } else if (b < 14006) {
        // pack: Bp4[(ft*64+d)*256 + pp*2 + u] = e2W[k=pp>>1][d*64 + ft*16 + (pp&1)*8 + u*4 ..]
        int idx = (b - 13750) * 256 + tid;   // 65536 float4s
        int u = idx & 1, pp = (idx >> 1) & 127, d = (idx >> 8) & 63, ft = idx >> 14;
        int k = pp >> 1, fo = (pp & 1) * 8 + u * 4;
        Bp4[idx] = *(const float4*)(e2W + (size_t)k * 4096 + d * 64 + ft * 16 + fo);
    } else if (b < 14294) {
        int idx = (b - 14006) * 256 + tid;
        if (idx < 32768) {                       // lWih [256][128] -> [128][256]
            int i = idx >> 8, r = idx & 255;
            lWihT[i * 256 + r] = lWih[r * 128 + i];
        } else if (idx < 49152) {                // lWhh [256][64] -> [64][256]
            int x2 = idx - 32768; int i = x2 >> 8, r = x2 & 255;
            lWhhT[i * 256 + r] = lWhh[r * 64 + i];
        } else if (idx < 61440) {                // gWih [192][64] -> [64][192]
            int x2 = idx - 49152; int i = x2 / 192, r = x2 % 192;
            gWihT[i * 192 + r] = gWih[r * 64 + i];
        } else if (idx < 73728) {                // gWhh [192][64] -> [64][192]
            int x2 = idx - 61440; int i = x2 / 192, r = x2 % 192;
            gWhhT[i * 192 + r] = gWhh[r * 64 + i];
        }
    } else {
        int n = (b - 14294) * 256 + tid;
        if (n < N_NODES) {
            int bb = batch[n];
            int pb = (n == 0) ? -1 : batch[n - 1];
            for (int g = pb + 1; g <= bb; ++g) gptr[g] = n;
            if (n == N_NODES - 1)
                for (int g = bb + 1; g <= N_GRAPHS; ++g) gptr[g] = N_NODES;
        }
    }
}

// ---------------- fused conv: 16 nodes x 16 f per block, 512 threads ----------------
// Phase A: thread owns (k, 4 nodes, 8 f): per d4-iter 4 broadcast ds_read_b128 feed
//          128 FMAs (0.5 B/FMA -> FMA-bound). 72.9KB LDS, 2 blocks/CU = 16 waves/CU.
// Phase B: flat tile edge range, 32 slots x 16 fi; dot64 via ds_read_b128.
__global__ __launch_bounds__(512, 4)
void conv_kernel(const float* __restrict__ node_h, const float* __restrict__ h1,
                 const float4* __restrict__ Bp4, const float* __restrict__ Tb_g,
                 const int* __restrict__ tptr, const int* __restrict__ edge_list,
                 const int* __restrict__ src, const int* __restrict__ dst,
                 float* __restrict__ agg) {
    __shared__ float A_s[16][64];
    __shared__ float Tb_s[16][16];
    __shared__ float T_lds[16 * 1060];   // [node]*1060 + [fi]*66 + k
    int bid = blockIdx.x;
    int nt = bid >> 2, ft = bid & 3;
    int n0 = nt * 16, f0 = ft * 16;
    int tid = threadIdx.x;

    if (tid < 256) {   // stage A-tile
        int nn = tid >> 4, d4 = (tid & 15) * 4;
        int n = n0 + nn;
        float4 v = make_float4(0.f, 0.f, 0.f, 0.f);
        if (n < N_NODES) v = *(const float4*)(node_h + (size_t)n * 64 + d4);
        *(float4*)(&A_s[nn][d4]) = v;
    } else {           // stage Tb
        int r = tid - 256;
        int nn = r >> 4, fi = r & 15;
        int n = n0 + nn;
        Tb_s[nn][fi] = (n < N_NODES) ? Tb_g[(size_t)n * 64 + f0 + fi] : 0.f;
    }
    __syncthreads();

    int pq = tid >> 7;                   // node quarter (0..3), 4 nodes each
    int pp = tid & 127;
    int k = pp >> 1;
    int fo = (pp & 1) * 8;               // this thread's 8 f's within the 16-wide tile
    int nb = pq * 4;
    const float4* BpP = Bp4 + (size_t)(ft * 64) * 256 + pp * 2;

    float acc[4][8];
    #pragma unroll
    for (int a = 0; a < 4; ++a)
        #pragma unroll
        for (int b2 = 0; b2 < 8; ++b2) acc[a][b2] = 0.f;

    float4 bpre[8];
    #pragma unroll
    for (int dd = 0; dd < 4; ++dd) {
        bpre[dd * 2]     = BpP[(size_t)dd * 256];
        bpre[dd * 2 + 1] = BpP[(size_t)dd * 256 + 1];
    }

    for (int d4 = 0; d4 < 64; d4 += 4) {
        float4 bcur[8];
        #pragma unroll
        for (int q = 0; q < 8; ++q) bcur[q] = bpre[q];
        if (d4 < 60) {
            #pragma unroll
            for (int dd = 0; dd < 4; ++dd) {
                bpre[dd * 2]     = BpP[(size_t)(d4 + 4 + dd) * 256];
                bpre[dd * 2 + 1] = BpP[(size_t)(d4 + 4 + dd) * 256 + 1];
            }
        }
        float4 A4[4];
        #pragma unroll
        for (int nn = 0; nn < 4; ++nn) A4[nn] = *(const float4*)(&A_s[nb + nn][d4]);
        #pragma unroll
        for (int dd = 0; dd < 4; ++dd) {
            float bv[8] = {bcur[dd*2].x, bcur[dd*2].y, bcur[dd*2].z, bcur[dd*2].w,
                           bcur[dd*2+1].x, bcur[dd*2+1].y, bcur[dd*2+1].z, bcur[dd*2+1].w};
            #pragma unroll
            for (int nn = 0; nn < 4; ++nn) {
                float a = (&A4[nn].x)[dd];
                #pragma unroll
                for (int j = 0; j < 8; ++j) acc[nn][j] += a * bv[j];
            }
        }
    }
    #pragma unroll
    for (int nn = 0; nn < 4; ++nn)
        #pragma unroll
        for (int j = 0; j < 8; ++j)
            T_lds[(nb + nn) * 1060 + (fo + j) * 66 + k] = acc[nn][j];
    __syncthreads();

    // Phase B: flat edge range for the whole 16-node tile
    int fi = tid & 15, slot = tid >> 4;   // 32 edge slots x 16 f
    int te0 = tptr[nt], te1 = tptr[nt + 1];
    for (int c = te0 + slot; c < te1; c += 32) {
        int e = edge_list[c];
        int nn = src[e] - n0;
        const float* h1e = h1 + (size_t)e * 64;
        const float* Tr = &T_lds[nn * 1060 + fi * 66];
        float s = Tb_s[nn][fi];
        #pragma unroll
        for (int k4 = 0; k4 < 64; k4 += 4) {
            float4 h4 = *(const float4*)(h1e + k4);
            float4 tv = *(const float4*)(Tr + k4);
            s += h4.x * tv.x + h4.y * tv.y + h4.z * tv.z + h4.w * tv.w;
        }
        atomicAdd(&agg[(size_t)dst[e] * 64 + f0 + fi], s);
    }
}

// ---------------- GRU + fused Tb recompute; re-zeroes agg for next conv ----------------
__global__ __launch_bounds__(192)
void gru_kernel(float* __restrict__ node_h, float* __restrict__ agg,
                const float* __restrict__ deg, const float* __restrict__ conv_b,
                const float* __restrict__ WihT, const float* __restrict__ WhhT,
                const float* __restrict__ bih, const float* __restrict__ bhh,
                const float* __restrict__ e2b, float* __restrict__ Tb_g, int want_tb) {
    __shared__ float m_s[64], h_s[64], gi_s[192], gh_s[192], hn_s[64], part[3][64];
    int j = threadIdx.x;  // 0..191 (gate-row)
    float wih[64], whh[64];
    #pragma unroll
    for (int d = 0; d < 64; ++d) {
        wih[d] = WihT[d * 192 + j];   // coalesced
        whh[d] = WhhT[d * 192 + j];
    }
    float bi = bih[j], bh = bhh[j];
    int dg2 = j >> 6, f2 = j & 63;
    int dlo = (dg2 == 0) ? 0 : (dg2 == 1 ? 22 : 43);
    int dhi = (dg2 == 0) ? 22 : (dg2 == 1 ? 43 : 64);
    for (int n = blockIdx.x; n < N_NODES; n += gridDim.x) {
        if (j < 64) {
            float dg = fmaxf(deg[n], 1.f);
            m_s[j] = fmaxf(agg[(size_t)n * 64 + j] / dg + conv_b[j], 0.f);
            agg[(size_t)n * 64 + j] = 0.f;   // re-zero for next conv (stream-ordered)
            h_s[j] = node_h[(size_t)n * 64 + j];
        }
        __syncthreads();
        float gi = bi, gh = bh;
        #pragma unroll
        for (int d4 = 0; d4 < 64; d4 += 4) {
            float4 m4 = *(const float4*)(&m_s[d4]);
            float4 h4 = *(const float4*)(&h_s[d4]);
            gi += m4.x * wih[d4] + m4.y * wih[d4 + 1] + m4.z * wih[d4 + 2] + m4.w * wih[d4 + 3];
            gh += h4.x * whh[d4] + h4.y * whh[d4 + 1] + h4.z * whh[d4 + 2] + h4.w * whh[d4 + 3];
        }
        gi_s[j] = gi; gh_s[j] = gh;
        __syncthreads();
        if (j < 64) {
            float r = sigmoidf_(gi_s[j] + gh_s[j]);
            float z = sigmoidf_(gi_s[j + 64] + gh_s[j + 64]);
            float nn = tanhf(gi_s[j + 128] + r * gh_s[j + 128]);
            float hnew = (1.f - z) * nn + z * h_s[j];
            node_h[(size_t)n * 64 + j] = hnew;
            hn_s[j] = hnew;
        }
        __syncthreads();
        if (want_tb) {
            float s = 0.f;
            for (int d = dlo; d < dhi; ++d) s += hn_s[d] * e2b[d * 64 + f2];
            part[dg2][f2] = s;
            __syncthreads();
            if (j < 64) Tb_g[(size_t)n * 64 + j] = part[0][j] + part[1][j] + part[2][j];
            __syncthreads();
        }
    }
}

// ---------------- Set2Set (all 3 steps) + output MLP, one block per graph ----------------
__global__ __launch_bounds__(64)
void s2s_kernel(const float* __restrict__ node_h, const int* __restrict__ gptr,
                const float* __restrict__ WihT, const float* __restrict__ WhhT,
                const float* __restrict__ bih, const float* __restrict__ bhh,
                const float* __restrict__ o1W, const float* __restrict__ o1b,
                const float* __restrict__ o2W, const float* __restrict__ o2b,
                float* __restrict__ z) {
    int g = blockIdx.x, t = threadIdx.x;
    __shared__ float qs[128], hs[64], q[64], wts[64];
    qs[t] = 0.f; qs[64 + t] = 0.f; hs[t] = 0.f;
    float c_t = 0.f;
    int nbeg = gptr[g], nend = gptr[g + 1];
    __syncthreads();
    for (int st = 0; st < 3; ++st) {
        float gv[4];
        #pragma unroll
        for (int gate = 0; gate < 4; ++gate) {
            int row = gate * 64 + t;
            float s = bih[row] + bhh[row];
            #pragma unroll 8
            for (int i = 0; i < 128; ++i) s += qs[i] * WihT[i * 256 + row];
            #pragma unroll 8
            for (int i = 0; i < 64; ++i) s += hs[i] * WhhT[i * 256 + row];
            gv[gate] = s;
        }
        float c = sigmoidf_(gv[1]) * c_t + sigmoidf_(gv[0]) * tanhf(gv[2]);
        float hn = sigmoidf_(gv[3]) * tanhf(c);
        c_t = c;
        __syncthreads();
        hs[t] = hn; q[t] = hn;
        __syncthreads();
        float rm = -INFINITY, rs = 0.f, racc = 0.f;
        for (int base = nbeg; base < nend; base += 64) {
            int n = base + t;
            float e = -INFINITY;
            if (n < nend) {
                float s = 0.f;
                #pragma unroll 8
                for (int f = 0; f < 64; ++f) s += node_h[(size_t)n * 64 + f] * q[f];
                e = s;
            }
            float cm = e;
            #pragma unroll
            for (int o = 32; o > 0; o >>= 1) cm = fmaxf(cm, __shfl_down(cm, o));
            cm = __shfl(cm, 0);
            float nm = fmaxf(rm, cm);
            float scale = (rm == -INFINITY) ? 0.f : expf(rm - nm);
            float wv = (n < nend) ? expf(e - nm) : 0.f;
            float cs = wv;
            #pragma unroll
            for (int o = 32; o > 0; o >>= 1) cs += __shfl_down(cs, o);
            cs = __shfl(cs, 0);
            wts[t] = wv;
            __syncthreads();
            float na = racc * scale;
            int cnt2 = min(64, nend - base);
            for (int l = 0; l < cnt2; ++l) na += wts[l] * node_h[(size_t)(base + l) * 64 + t];
            racc = na;
            rs = rs * scale + cs;
            rm = nm;
            __syncthreads();
        }
        float r = (nend > nbeg) ? racc / rs : 0.f;
        qs[t] = q[t];
        qs[64 + t] = r;
        __syncthreads();
    }
    // output MLP with 64 threads: rows {t, t+64}
    float sA = o1b[t], sB = o1b[t + 64];
    #pragma unroll 8
    for (int i = 0; i < 128; ++i) {
        float qv = qs[i];
        sA += qv * o1W[i * 128 + t];
        sB += qv * o1W[i * 128 + t + 64];
    }
    float red = fmaxf(sA, 0.f) * o2W[t] + fmaxf(sB, 0.f) * o2W[t + 64];
    #pragma unroll
    for (int o = 32; o > 0; o >>= 1) red += __shfl_down(red, o);
    if (t == 0) z[g] = red + o2b[0];
}

extern "C" void kernel_launch(void* const* d_in, const int* in_sizes, int n_in,
                              void* d_out, int out_size, void* d_ws, size_t ws_size,
                              hipStream_t stream) {
    const float* x         = (const float*)d_in[0];
    const float* edge_attr = (const float*)d_in[1];
    const int*   ei        = (const int*)d_in[2];
    const int*   batch     = (const int*)d_in[3];
    const float* in_W      = (const float*)d_in[4];
    const float* in_b      = (const float*)d_in[5];
    const float* e1_W      = (const float*)d_in[6];
    const float* e1_b      = (const float*)d_in[7];
    const float* e2_W      = (const float*)d_in[8];
    const float* e2_b      = (const float*)d_in[9];
    const float* conv_b    = (const float*)d_in[10];
    const float* gWih      = (const float*)d_in[11];
    const float* gWhh      = (const float*)d_in[12];
    const float* gbih      = (const float*)d_in[13];
    const float* gbhh      = (const float*)d_in[14];
    const float* lWih      = (const float*)d_in[15];
    const float* lWhh      = (const float*)d_in[16];
    const float* lbih      = (const float*)d_in[17];
    const float* lbhh      = (const float*)d_in[18];
    const float* o1W       = (const float*)d_in[19];
    const float* o1b       = (const float*)d_in[20];
    const float* o2W       = (const float*)d_in[21];
    const float* o2b       = (const float*)d_in[22];
    const int* src = ei;
    const int* dst = ei + N_EDGES;
    float* z = (float*)d_out;

    char* ws = (char*)d_ws;
    size_t off = 0;
    auto alloc = [&](size_t bytes) {
        void* p = ws + off;
        off = (off + bytes + 255) & ~(size_t)255;
        return p;
    };
    float* node_h   = (float*)alloc((size_t)N_NODES * 64 * 4);
    float* agg      = (float*)alloc((size_t)N_NODES * 64 * 4);
    float* h1       = (float*)alloc((size_t)N_EDGES * 64 * 4);
    float* Bp       = (float*)alloc((size_t)4 * 64 * 256 * 4 * 4);   // packed e2_W, 1 MB
    float* Tb_g     = (float*)alloc((size_t)N_NODES * 64 * 4);
    float* lWihT    = (float*)alloc(128 * 256 * 4);
    float* lWhhT    = (float*)alloc(64 * 256 * 4);
    float* gWihT    = (float*)alloc(64 * 192 * 4);
    float* gWhhT    = (float*)alloc(64 * 192 * 4);
    float* deg      = (float*)alloc(N_NODES * 4);       // deg,tcnt adjacent (one memset)
    int*   tcnt     = (int*)alloc((N_TILES + 2) * 4);
    int*   tcursor  = (int*)alloc((N_TILES + 2) * 4);
    int*   tptr     = (int*)alloc((N_TILES + 1) * 4);
    int*   edge_list= (int*)alloc(N_EDGES * 4);
    int*   gptr     = (int*)alloc((N_GRAPHS + 1) * 4);

    size_t degpad = ((size_t)N_NODES * 4 + 255) & ~(size_t)255;
    hipMemsetAsync(deg, 0, degpad + (N_TILES + 2) * 4, stream);   // deg + tcnt
    hipMemsetAsync(agg, 0, (size_t)N_NODES * 64 * 4, stream);     // once; gru re-zeroes

    count_kernel<<<(N_EDGES + 255) / 256, 256, 0, stream>>>(src, dst, tcnt, deg);
    tscan_kernel<<<1, 1024, 0, stream>>>(tcnt, tptr, tcursor);
    fill_kernel<<<(N_EDGES + 255) / 256, 256, 0, stream>>>(src, tcursor, edge_list);
    prep_kernel<<<14353, 256, 0, stream>>>(x, in_W, in_b, node_h, e2_b, Tb_g,
                                           edge_attr, e1_W, e1_b, h1,
                                           e2_W, (float4*)Bp,
                                           lWih, lWhh, gWih, gWhh,
                                           lWihT, lWhhT, gWihT, gWhhT,
                                           batch, gptr);

    for (int it = 0; it < 3; ++it) {
        conv_kernel<<<N_TILES * 4, 512, 0, stream>>>(node_h, h1, (const float4*)Bp, Tb_g,
                                                     tptr, edge_list, src, dst, agg);
        gru_kernel<<<512, 192, 0, stream>>>(node_h, agg, deg, conv_b,
                                            gWihT, gWhhT, gbih, gbhh,
                                            e2_b, Tb_g, (it < 2) ? 1 : 0);
    }
    s2s_kernel<<<N_GRAPHS, 64, 0, stream>>>(node_h, gptr, lWihT, lWhhT, lbih, lbhh,
                                            o1W, o1b, o2W, o2b, z);
}

// Round 6
// 730.102 us; speedup vs baseline: 1.4103x; 1.4103x over previous
//
#include <hip/hip_runtime.h>
#include <math.h>

#define N_NODES 15000
#define N_EDGES 40000
#define N_GRAPHS 750
#define N_TILES 938   // ceil(15000/16)

typedef __attribute__((ext_vector_type(8))) short bf16x8;
typedef __attribute__((ext_vector_type(4))) float f32x4;

__device__ __forceinline__ float sigmoidf_(float x) { return 1.f / (1.f + expf(-x)); }

// round-to-nearest-even fp32 -> bf16 bits
__device__ __forceinline__ unsigned short f2bf(float v) {
    unsigned u = __float_as_uint(v);
    unsigned r = (u + 0x7FFFu + ((u >> 16) & 1u)) >> 16;
    return (unsigned short)r;
}
__device__ __forceinline__ float bf2f(unsigned short b) {
    return __uint_as_float(((unsigned)b) << 16);
}

// ---------------- CSR prep ----------------
__global__ void count_kernel(const int* __restrict__ src, const int* __restrict__ dst,
                             int* __restrict__ tcnt, float* __restrict__ deg) {
    int e = blockIdx.x * 256 + threadIdx.x;
    if (e >= N_EDGES) return;
    atomicAdd(&tcnt[src[e] >> 4], 1);
    atomicAdd(&deg[dst[e]], 1.f);
}

__global__ void tscan_kernel(const int* __restrict__ tcnt, int* __restrict__ tptr,
                             int* __restrict__ cursor) {
    __shared__ int buf[1024];
    int t = threadIdx.x;
    int v = (t < N_TILES) ? tcnt[t] : 0;
    buf[t] = v;
    __syncthreads();
    for (int ofs = 1; ofs < 1024; ofs <<= 1) {
        int a = (t >= ofs) ? buf[t - ofs] : 0;
        __syncthreads();
        buf[t] += a;
        __syncthreads();
    }
    if (t < N_TILES) {
        int excl = buf[t] - v;
        tptr[t] = excl;
        cursor[t] = excl;
    }
    if (t == N_TILES - 1) tptr[N_TILES] = buf[t];
}

__global__ void fill_kernel(const int* __restrict__ src, int* __restrict__ cursor,
                            int* __restrict__ edge_list) {
    int e = blockIdx.x * 256 + threadIdx.x;
    if (e >= N_EDGES) return;
    int slot = atomicAdd(&cursor[src[e] >> 4], 1);
    edge_list[slot] = e;
}

// ---------------- fused prep mega-kernel (block-range partitioned) ----------------
// [0,3750): proj + initial Tb. [3750,13750): h1. [13750,14774): bf16 hi/lo pack of e2_W
// into MFMA B-operand lane order. [14774,15062): transpose recurrent weights.
// [15062,15121): gptr.
__global__ __launch_bounds__(256)
void prep_kernel(const float* __restrict__ x, const float* __restrict__ in_W,
                 const float* __restrict__ in_b, float* __restrict__ node_h,
                 const float* __restrict__ e2b, float* __restrict__ Tb_g,
                 const float* __restrict__ ea, const float* __restrict__ e1_W,
                 const float* __restrict__ e1_b, float* __restrict__ h1,
                 const float* __restrict__ e2W,
                 unsigned short* __restrict__ Bhi, unsigned short* __restrict__ Blo,
                 const float* __restrict__ lWih, const float* __restrict__ lWhh,
                 const float* __restrict__ gWih, const float* __restrict__ gWhh,
                 float* __restrict__ lWihT, float* __restrict__ lWhhT,
                 float* __restrict__ gWihT, float* __restrict__ gWhhT,
                 const int* __restrict__ batch, int* __restrict__ gptr) {
    int b = blockIdx.x;
    int tid = threadIdx.x;
    if (b < 3750) {
        __shared__ float xs[4][32];
        __shared__ float hrow[4][64];
        int n0 = b * 4;
        if (tid < 128) xs[tid >> 5][tid & 31] = x[n0 * 32 + tid];
        __syncthreads();
        int nn = tid >> 6, f = tid & 63;
        float s = in_b[f];
        #pragma unroll
        for (int i = 0; i < 32; ++i) s += xs[nn][i] * in_W[i * 64 + f];
        s = fmaxf(s, 0.f);
        node_h[(size_t)(n0 + nn) * 64 + f] = s;
        hrow[nn][f] = s;
        __syncthreads();
        float t2 = 0.f;
        #pragma unroll 8
        for (int d = 0; d < 64; ++d) t2 += hrow[nn][d] * e2b[d * 64 + f];
        Tb_g[(size_t)(n0 + nn) * 64 + f] = t2;
    } else if (b < 13750) {
        __shared__ float eas[4][16];
        int e0 = (b - 3750) * 4;
        if (tid < 64) eas[tid >> 4][tid & 15] = ea[e0 * 16 + tid];
        __syncthreads();
        int nn = tid >> 6, f = tid & 63;
        float s = e1_b[f];
        #pragma unroll
        for (int i = 0; i < 16; ++i) s += eas[nn][i] * e1_W[i * 64 + f];
        h1[(size_t)(e0 + nn) * 64 + f] = fmaxf(s, 0.f);
    } else if (b < 14774) {
        // bf16 split pack. idx layout matches conv's frag load:
        //   shorts base = (((ft*32+ct)*2+kt)*64 + lane)*8 + j
        // element = Bmat[d][c] = e2W[kk][d*64 + ft*8 + fi], d=kt*32+quad*8+j,
        //   c = ct*16 + (lane&15), kk=c>>3, fi=c&7.
        int idx = (b - 13750) * 256 + tid;           // [0, 262144)
        int j = idx & 7, lane = (idx >> 3) & 63, kt = (idx >> 9) & 1;
        int ct = (idx >> 10) & 31, ft = idx >> 15;
        int d = kt * 32 + ((lane >> 4) << 3) + j;
        int c = ct * 16 + (lane & 15);
        int kk = c >> 3, fi = c & 7;
        float v = e2W[(size_t)kk * 4096 + d * 64 + ft * 8 + fi];
        unsigned short hi = f2bf(v);
        unsigned short lo = f2bf(v - bf2f(hi));
        Bhi[idx] = hi;
        Blo[idx] = lo;
    } else if (b < 15062) {
        int idx = (b - 14774) * 256 + tid;
        if (idx < 32768) {                       // lWih [256][128] -> [128][256]
            int i = idx >> 8, r = idx & 255;
            lWihT[i * 256 + r] = lWih[r * 128 + i];
        } else if (idx < 49152) {                // lWhh [256][64] -> [64][256]
            int x2 = idx - 32768; int i = x2 >> 8, r = x2 & 255;
            lWhhT[i * 256 + r] = lWhh[r * 64 + i];
        } else if (idx < 61440) {                // gWih [192][64] -> [64][192]
            int x2 = idx - 49152; int i = x2 / 192, r = x2 % 192;
            gWihT[i * 192 + r] = gWih[r * 64 + i];
        } else if (idx < 73728) {                // gWhh [192][64] -> [64][192]
            int x2 = idx - 61440; int i = x2 / 192, r = x2 % 192;
            gWhhT[i * 192 + r] = gWhh[r * 64 + i];
        }
    } else {
        int n = (b - 15062) * 256 + tid;
        if (n < N_NODES) {
            int bb = batch[n];
            int pb = (n == 0) ? -1 : batch[n - 1];
            for (int g = pb + 1; g <= bb; ++g) gptr[g] = n;
            if (n == N_NODES - 1)
                for (int g = bb + 1; g <= N_GRAPHS; ++g) gptr[g] = N_NODES;
        }
    }
}

// ---------------- fused conv: MFMA phase A + flat message scatter ----------------
// Grid: 938 node-tiles (16 nodes) x 8 f-tiles (8 f). Block 256 = 4 waves.
// Phase A: T[16n x 512(kk*8+fi)] = A[16x64d] @ Bslab[64d x 512] via
//   mfma_f32_16x16x32_bf16, 2-term bf16 split (all 4 cross products, exact to ~2^-18
//   input rounding). Each wave owns 8 of 32 col-tiles; A-frags built from LDS;
//   B-frags streamed from pre-packed global (bf16, lane-ordered, L1-resident).
// Phase B: flat tile edge range; msg = Tb + dot64(h1[e,:], T[nn,fi,:]); atomicAdd.
__global__ __launch_bounds__(256, 4)
void conv_kernel(const float* __restrict__ node_h, const float* __restrict__ h1,
                 const unsigned short* __restrict__ Bhi, const unsigned short* __restrict__ Blo,
                 const float* __restrict__ Tb_g,
                 const int* __restrict__ tptr, const int* __restrict__ edge_list,
                 const int* __restrict__ src, const int* __restrict__ dst,
                 float* __restrict__ agg) {
    __shared__ float A_s[16][68];        // padded: (m*68)%32 = 4m -> 2-way max (free)
    __shared__ float Tb_s[16][8];
    __shared__ float T_lds[16 * 544];    // [node]*544 + [fi]*68 + kk ; 68 = 16B-aligned
    int bid = blockIdx.x;
    int nt = bid >> 3, ft = bid & 7;
    int n0 = nt * 16;
    int tid = threadIdx.x;

    {   // stage A-tile (fp32)
        int nn = tid >> 4, d4 = (tid & 15) * 4;
        int n = n0 + nn;
        float4 v = make_float4(0.f, 0.f, 0.f, 0.f);
        if (n < N_NODES) v = *(const float4*)(node_h + (size_t)n * 64 + d4);
        *(float4*)(&A_s[nn][d4]) = v;
    }
    if (tid < 128) {
        int nn = tid >> 3, fi = tid & 7;
        int n = n0 + nn;
        Tb_s[nn][fi] = (n < N_NODES) ? Tb_g[(size_t)n * 64 + ft * 8 + fi] : 0.f;
    }
    __syncthreads();

    int lane = tid & 63, wave = tid >> 6;
    int quad = lane >> 4, m = lane & 15;

    // A-fragments: A[m][k = quad*8+j], k-halves kt=0,1; split hi/lo
    bf16x8 ahi[2], alo[2];
    #pragma unroll
    for (int kt = 0; kt < 2; ++kt) {
        const float* ap = &A_s[m][kt * 32 + quad * 8];
        float4 x0 = *(const float4*)ap;
        float4 x1 = *(const float4*)(ap + 4);
        float av[8] = {x0.x, x0.y, x0.z, x0.w, x1.x, x1.y, x1.z, x1.w};
        #pragma unroll
        for (int j = 0; j < 8; ++j) {
            unsigned short hi = f2bf(av[j]);
            unsigned short lo = f2bf(av[j] - bf2f(hi));
            ahi[kt][j] = (short)hi;
            alo[kt][j] = (short)lo;
        }
    }

    // MFMA over this wave's 8 column-tiles
    int c0 = ft * 32;   // first col-tile index of this f-tile in packed B
    #pragma unroll 1
    for (int ci = 0; ci < 8; ++ci) {
        int ct = wave * 8 + ci;
        f32x4 acc = {0.f, 0.f, 0.f, 0.f};
        #pragma unroll
        for (int kt = 0; kt < 2; ++kt) {
            size_t base = ((size_t)((c0 + ct) * 2 + kt) * 64 + lane) * 8;
            bf16x8 bh = *(const bf16x8*)(Bhi + base);
            bf16x8 bl = *(const bf16x8*)(Blo + base);
            acc = __builtin_amdgcn_mfma_f32_16x16x32_bf16(ahi[kt], bh, acc, 0, 0, 0);
            acc = __builtin_amdgcn_mfma_f32_16x16x32_bf16(alo[kt], bh, acc, 0, 0, 0);
            acc = __builtin_amdgcn_mfma_f32_16x16x32_bf16(ahi[kt], bl, acc, 0, 0, 0);
            acc = __builtin_amdgcn_mfma_f32_16x16x32_bf16(alo[kt], bl, acc, 0, 0, 0);
        }
        // C/D layout: col = lane&15, row = quad*4 + r
        int c = ct * 16 + m;
        int kk = c >> 3, fi = c & 7;
        #pragma unroll
        for (int r = 0; r < 4; ++r)
            T_lds[(quad * 4 + r) * 544 + fi * 68 + kk] = acc[r];
    }
    __syncthreads();

    // Phase B: flat edge range for the whole 16-node tile
    int fi = tid & 7, slot = tid >> 3;   // 32 edge slots x 8 f
    int te0 = tptr[nt], te1 = tptr[nt + 1];
    for (int c = te0 + slot; c < te1; c += 32) {
        int e = edge_list[c];
        int nn = src[e] - n0;
        const float* h1e = h1 + (size_t)e * 64;
        const float* Tr = &T_lds[nn * 544 + fi * 68];
        float s = Tb_s[nn][fi];
        #pragma unroll
        for (int k4 = 0; k4 < 64; k4 += 4) {
            float4 h4 = *(const float4*)(h1e + k4);
            float4 tv = *(const float4*)(Tr + k4);
            s += h4.x * tv.x + h4.y * tv.y + h4.z * tv.z + h4.w * tv.w;
        }
        atomicAdd(&agg[(size_t)dst[e] * 64 + ft * 8 + fi], s);
    }
}

// ---------------- GRU + fused Tb recompute; re-zeroes agg for next conv ----------------
__global__ __launch_bounds__(192)
void gru_kernel(float* __restrict__ node_h, float* __restrict__ agg,
                const float* __restrict__ deg, const float* __restrict__ conv_b,
                const float* __restrict__ WihT, const float* __restrict__ WhhT,
                const float* __restrict__ bih, const float* __restrict__ bhh,
                const float* __restrict__ e2b, float* __restrict__ Tb_g, int want_tb) {
    __shared__ float m_s[64], h_s[64], gi_s[192], gh_s[192], hn_s[64], part[3][64];
    int j = threadIdx.x;  // 0..191 (gate-row)
    float wih[64], whh[64];
    #pragma unroll
    for (int d = 0; d < 64; ++d) {
        wih[d] = WihT[d * 192 + j];   // coalesced
        whh[d] = WhhT[d * 192 + j];
    }
    float bi = bih[j], bh = bhh[j];
    int dg2 = j >> 6, f2 = j & 63;
    int dlo = (dg2 == 0) ? 0 : (dg2 == 1 ? 22 : 43);
    int dhi = (dg2 == 0) ? 22 : (dg2 == 1 ? 43 : 64);
    for (int n = blockIdx.x; n < N_NODES; n += gridDim.x) {
        if (j < 64) {
            float dg = fmaxf(deg[n], 1.f);
            m_s[j] = fmaxf(agg[(size_t)n * 64 + j] / dg + conv_b[j], 0.f);
            agg[(size_t)n * 64 + j] = 0.f;   // re-zero for next conv (stream-ordered)
            h_s[j] = node_h[(size_t)n * 64 + j];
        }
        __syncthreads();
        float gi = bi, gh = bh;
        #pragma unroll
        for (int d4 = 0; d4 < 64; d4 += 4) {
            float4 m4 = *(const float4*)(&m_s[d4]);
            float4 h4 = *(const float4*)(&h_s[d4]);
            gi += m4.x * wih[d4] + m4.y * wih[d4 + 1] + m4.z * wih[d4 + 2] + m4.w * wih[d4 + 3];
            gh += h4.x * whh[d4] + h4.y * whh[d4 + 1] + h4.z * whh[d4 + 2] + h4.w * whh[d4 + 3];
        }
        gi_s[j] = gi; gh_s[j] = gh;
        __syncthreads();
        if (j < 64) {
            float r = sigmoidf_(gi_s[j] + gh_s[j]);
            float z = sigmoidf_(gi_s[j + 64] + gh_s[j + 64]);
            float nn = tanhf(gi_s[j + 128] + r * gh_s[j + 128]);
            float hnew = (1.f - z) * nn + z * h_s[j];
            node_h[(size_t)n * 64 + j] = hnew;
            hn_s[j] = hnew;
        }
        __syncthreads();
        if (want_tb) {
            float s = 0.f;
            for (int d = dlo; d < dhi; ++d) s += hn_s[d] * e2b[d * 64 + f2];
            part[dg2][f2] = s;
            __syncthreads();
            if (j < 64) Tb_g[(size_t)n * 64 + j] = part[0][j] + part[1][j] + part[2][j];
            __syncthreads();
        }
    }
}

// ---------------- Set2Set (all 3 steps) + output MLP, one block per graph ----------------
__global__ __launch_bounds__(64)
void s2s_kernel(const float* __restrict__ node_h, const int* __restrict__ gptr,
                const float* __restrict__ WihT, const float* __restrict__ WhhT,
                const float* __restrict__ bih, const float* __restrict__ bhh,
                const float* __restrict__ o1W, const float* __restrict__ o1b,
                const float* __restrict__ o2W, const float* __restrict__ o2b,
                float* __restrict__ z) {
    int g = blockIdx.x, t = threadIdx.x;
    __shared__ float qs[128], hs[64], q[64], wts[64];
    qs[t] = 0.f; qs[64 + t] = 0.f; hs[t] = 0.f;
    float c_t = 0.f;
    int nbeg = gptr[g], nend = gptr[g + 1];
    __syncthreads();
    for (int st = 0; st < 3; ++st) {
        float gv[4];
        #pragma unroll
        for (int gate = 0; gate < 4; ++gate) {
            int row = gate * 64 + t;
            float s = bih[row] + bhh[row];
            #pragma unroll 8
            for (int i = 0; i < 128; ++i) s += qs[i] * WihT[i * 256 + row];
            #pragma unroll 8
            for (int i = 0; i < 64; ++i) s += hs[i] * WhhT[i * 256 + row];
            gv[gate] = s;
        }
        float c = sigmoidf_(gv[1]) * c_t + sigmoidf_(gv[0]) * tanhf(gv[2]);
        float hn = sigmoidf_(gv[3]) * tanhf(c);
        c_t = c;
        __syncthreads();
        hs[t] = hn; q[t] = hn;
        __syncthreads();
        float rm = -INFINITY, rs = 0.f, racc = 0.f;
        for (int base = nbeg; base < nend; base += 64) {
            int n = base + t;
            float e = -INFINITY;
            if (n < nend) {
                float s = 0.f;
                #pragma unroll 8
                for (int f = 0; f < 64; ++f) s += node_h[(size_t)n * 64 + f] * q[f];
                e = s;
            }
            float cm = e;
            #pragma unroll
            for (int o = 32; o > 0; o >>= 1) cm = fmaxf(cm, __shfl_down(cm, o));
            cm = __shfl(cm, 0);
            float nm = fmaxf(rm, cm);
            float scale = (rm == -INFINITY) ? 0.f : expf(rm - nm);
            float wv = (n < nend) ? expf(e - nm) : 0.f;
            float cs = wv;
            #pragma unroll
            for (int o = 32; o > 0; o >>= 1) cs += __shfl_down(cs, o);
            cs = __shfl(cs, 0);
            wts[t] = wv;
            __syncthreads();
            float na = racc * scale;
            int cnt2 = min(64, nend - base);
            for (int l = 0; l < cnt2; ++l) na += wts[l] * node_h[(size_t)(base + l) * 64 + t];
            racc = na;
            rs = rs * scale + cs;
            rm = nm;
            __syncthreads();
        }
        float r = (nend > nbeg) ? racc / rs : 0.f;
        qs[t] = q[t];
        qs[64 + t] = r;
        __syncthreads();
    }
    float sA = o1b[t], sB = o1b[t + 64];
    #pragma unroll 8
    for (int i = 0; i < 128; ++i) {
        float qv = qs[i];
        sA += qv * o1W[i * 128 + t];
        sB += qv * o1W[i * 128 + t + 64];
    }
    float red = fmaxf(sA, 0.f) * o2W[t] + fmaxf(sB, 0.f) * o2W[t + 64];
    #pragma unroll
    for (int o = 32; o > 0; o >>= 1) red += __shfl_down(red, o);
    if (t == 0) z[g] = red + o2b[0];
}

extern "C" void kernel_launch(void* const* d_in, const int* in_sizes, int n_in,
                              void* d_out, int out_size, void* d_ws, size_t ws_size,
                              hipStream_t stream) {
    const float* x         = (const float*)d_in[0];
    const float* edge_attr = (const float*)d_in[1];
    const int*   ei        = (const int*)d_in[2];
    const int*   batch     = (const int*)d_in[3];
    const float* in_W      = (const float*)d_in[4];
    const float* in_b      = (const float*)d_in[5];
    const float* e1_W      = (const float*)d_in[6];
    const float* e1_b      = (const float*)d_in[7];
    const float* e2_W      = (const float*)d_in[8];
    const float* e2_b      = (const float*)d_in[9];
    const float* conv_b    = (const float*)d_in[10];
    const float* gWih      = (const float*)d_in[11];
    const float* gWhh      = (const float*)d_in[12];
    const float* gbih      = (const float*)d_in[13];
    const float* gbhh      = (const float*)d_in[14];
    const float* lWih      = (const float*)d_in[15];
    const float* lWhh      = (const float*)d_in[16];
    const float* lbih      = (const float*)d_in[17];
    const float* lbhh      = (const float*)d_in[18];
    const float* o1W       = (const float*)d_in[19];
    const float* o1b       = (const float*)d_in[20];
    const float* o2W       = (const float*)d_in[21];
    const float* o2b       = (const float*)d_in[22];
    const int* src = ei;
    const int* dst = ei + N_EDGES;
    float* z = (float*)d_out;

    char* ws = (char*)d_ws;
    size_t off = 0;
    auto alloc = [&](size_t bytes) {
        void* p = ws + off;
        off = (off + bytes + 255) & ~(size_t)255;
        return p;
    };
    float* node_h   = (float*)alloc((size_t)N_NODES * 64 * 4);
    float* agg      = (float*)alloc((size_t)N_NODES * 64 * 4);
    float* h1       = (float*)alloc((size_t)N_EDGES * 64 * 4);
    unsigned short* Bhi = (unsigned short*)alloc((size_t)262144 * 2);  // packed bf16 hi
    unsigned short* Blo = (unsigned short*)alloc((size_t)262144 * 2);  // packed bf16 lo
    float* Tb_g     = (float*)alloc((size_t)N_NODES * 64 * 4);
    float* lWihT    = (float*)alloc(128 * 256 * 4);
    float* lWhhT    = (float*)alloc(64 * 256 * 4);
    float* gWihT    = (float*)alloc(64 * 192 * 4);
    float* gWhhT    = (float*)alloc(64 * 192 * 4);
    float* deg      = (float*)alloc(N_NODES * 4);       // deg,tcnt adjacent (one memset)
    int*   tcnt     = (int*)alloc((N_TILES + 2) * 4);
    int*   tcursor  = (int*)alloc((N_TILES + 2) * 4);
    int*   tptr     = (int*)alloc((N_TILES + 1) * 4);
    int*   edge_list= (int*)alloc(N_EDGES * 4);
    int*   gptr     = (int*)alloc((N_GRAPHS + 1) * 4);

    size_t degpad = ((size_t)N_NODES * 4 + 255) & ~(size_t)255;
    hipMemsetAsync(deg, 0, degpad + (N_TILES + 2) * 4, stream);   // deg + tcnt
    hipMemsetAsync(agg, 0, (size_t)N_NODES * 64 * 4, stream);     // once; gru re-zeroes

    count_kernel<<<(N_EDGES + 255) / 256, 256, 0, stream>>>(src, dst, tcnt, deg);
    tscan_kernel<<<1, 1024, 0, stream>>>(tcnt, tptr, tcursor);
    fill_kernel<<<(N_EDGES + 255) / 256, 256, 0, stream>>>(src, tcursor, edge_list);
    prep_kernel<<<15121, 256, 0, stream>>>(x, in_W, in_b, node_h, e2_b, Tb_g,
                                           edge_attr, e1_W, e1_b, h1,
                                           e2_W, Bhi, Blo,
                                           lWih, lWhh, gWih, gWhh,
                                           lWihT, lWhhT, gWihT, gWhhT,
                                           batch, gptr);

    for (int it = 0; it < 3; ++it) {
        conv_kernel<<<N_TILES * 8, 256, 0, stream>>>(node_h, h1, Bhi, Blo, Tb_g,
                                                     tptr, edge_list, src, dst, agg);
        gru_kernel<<<512, 192, 0, stream>>>(node_h, agg, deg, conv_b,
                                            gWihT, gWhhT, gbih, gbhh,
                                            e2_b, Tb_g, (it < 2) ? 1 : 0);
    }
    s2s_kernel<<<N_GRAPHS, 64, 0, stream>>>(node_h, gptr, lWihT, lWhhT, lbih, lbhh,
                                            o1W, o1b, o2W, o2b, z);
}

// Round 7
// 539.257 us; speedup vs baseline: 1.9094x; 1.3539x over previous
//
#include <hip/hip_runtime.h>
#include <math.h>

#define N_NODES 15000
#define N_EDGES 40000
#define N_GRAPHS 750
#define N_TILES 938   // ceil(15000/16)

typedef __attribute__((ext_vector_type(8))) short bf16x8;
typedef __attribute__((ext_vector_type(4))) float f32x4;

__device__ __forceinline__ float sigmoidf_(float x) { return 1.f / (1.f + expf(-x)); }

// round-to-nearest-even fp32 -> bf16 bits
__device__ __forceinline__ unsigned short f2bf(float v) {
    unsigned u = __float_as_uint(v);
    unsigned r = (u + 0x7FFFu + ((u >> 16) & 1u)) >> 16;
    return (unsigned short)r;
}
__device__ __forceinline__ float bf2f(unsigned short b) {
    return __uint_as_float(((unsigned)b) << 16);
}

// ---------------- CSR prep ----------------
__global__ void count_kernel(const int* __restrict__ src, const int* __restrict__ dst,
                             int* __restrict__ tcnt, float* __restrict__ deg) {
    int e = blockIdx.x * 256 + threadIdx.x;
    if (e >= N_EDGES) return;
    atomicAdd(&tcnt[src[e] >> 4], 1);
    atomicAdd(&deg[dst[e]], 1.f);
}

__global__ void tscan_kernel(const int* __restrict__ tcnt, int* __restrict__ tptr,
                             int* __restrict__ cursor) {
    __shared__ int buf[1024];
    int t = threadIdx.x;
    int v = (t < N_TILES) ? tcnt[t] : 0;
    buf[t] = v;
    __syncthreads();
    for (int ofs = 1; ofs < 1024; ofs <<= 1) {
        int a = (t >= ofs) ? buf[t - ofs] : 0;
        __syncthreads();
        buf[t] += a;
        __syncthreads();
    }
    if (t < N_TILES) {
        int excl = buf[t] - v;
        tptr[t] = excl;
        cursor[t] = excl;
    }
    if (t == N_TILES - 1) tptr[N_TILES] = buf[t];
}

__global__ void fill_kernel(const int* __restrict__ src, int* __restrict__ cursor,
                            int* __restrict__ edge_list) {
    int e = blockIdx.x * 256 + threadIdx.x;
    if (e >= N_EDGES) return;
    int slot = atomicAdd(&cursor[src[e] >> 4], 1);
    edge_list[slot] = e;
}

// ---------------- fused prep mega-kernel (block-range partitioned) ----------------
// [0,3750): proj + initial Tb. [3750,13750): h1. [13750,14774): conv e2_W bf16 pack.
// [14774,14966): LSTM weight transposes. [14966,15078): gru/e2b MFMA packs.
// [15078,15137): gptr.
__global__ __launch_bounds__(256)
void prep_kernel(const float* __restrict__ x, const float* __restrict__ in_W,
                 const float* __restrict__ in_b, float* __restrict__ node_h,
                 const float* __restrict__ e2b, float* __restrict__ Tb_g,
                 const float* __restrict__ ea, const float* __restrict__ e1_W,
                 const float* __restrict__ e1_b, float* __restrict__ h1,
                 const float* __restrict__ e2W,
                 unsigned short* __restrict__ Bhi, unsigned short* __restrict__ Blo,
                 const float* __restrict__ lWih, const float* __restrict__ lWhh,
                 const float* __restrict__ gWih, const float* __restrict__ gWhh,
                 float* __restrict__ lWihT, float* __restrict__ lWhhT,
                 unsigned short* __restrict__ gWihP, unsigned short* __restrict__ gWhhP,
                 unsigned short* __restrict__ e2bP,
                 const int* __restrict__ batch, int* __restrict__ gptr) {
    int b = blockIdx.x;
    int tid = threadIdx.x;
    if (b < 3750) {
        __shared__ float xs[4][32];
        __shared__ float hrow[4][64];
        int n0 = b * 4;
        if (tid < 128) xs[tid >> 5][tid & 31] = x[n0 * 32 + tid];
        __syncthreads();
        int nn = tid >> 6, f = tid & 63;
        float s = in_b[f];
        #pragma unroll
        for (int i = 0; i < 32; ++i) s += xs[nn][i] * in_W[i * 64 + f];
        s = fmaxf(s, 0.f);
        node_h[(size_t)(n0 + nn) * 64 + f] = s;
        hrow[nn][f] = s;
        __syncthreads();
        float t2 = 0.f;
        #pragma unroll 8
        for (int d = 0; d < 64; ++d) t2 += hrow[nn][d] * e2b[d * 64 + f];
        Tb_g[(size_t)(n0 + nn) * 64 + f] = t2;
    } else if (b < 13750) {
        __shared__ float eas[4][16];
        int e0 = (b - 3750) * 4;
        if (tid < 64) eas[tid >> 4][tid & 15] = ea[e0 * 16 + tid];
        __syncthreads();
        int nn = tid >> 6, f = tid & 63;
        float s = e1_b[f];
        #pragma unroll
        for (int i = 0; i < 16; ++i) s += eas[nn][i] * e1_W[i * 64 + f];
        h1[(size_t)(e0 + nn) * 64 + f] = fmaxf(s, 0.f);
    } else if (b < 14774) {
        // conv B pack: shorts base = (((ft*32+ct)*2+kt)*64 + lane)*8 + j
        int idx = (b - 13750) * 256 + tid;           // [0, 262144)
        int j = idx & 7, lane = (idx >> 3) & 63, kt = (idx >> 9) & 1;
        int ct = (idx >> 10) & 31, ft = idx >> 15;
        int d = kt * 32 + ((lane >> 4) << 3) + j;
        int c = ct * 16 + (lane & 15);
        int kk = c >> 3, fi = c & 7;
        float v = e2W[(size_t)kk * 4096 + d * 64 + ft * 8 + fi];
        unsigned short hi = f2bf(v);
        Bhi[idx] = hi;
        Blo[idx] = f2bf(v - bf2f(hi));
    } else if (b < 14966) {
        int idx = (b - 14774) * 256 + tid;
        if (idx < 32768) {                       // lWih [256][128] -> [128][256]
            int i = idx >> 8, r = idx & 255;
            lWihT[i * 256 + r] = lWih[r * 128 + i];
        } else if (idx < 49152) {                // lWhh [256][64] -> [64][256]
            int x2 = idx - 32768; int i = x2 >> 8, r = x2 & 255;
            lWhhT[i * 256 + r] = lWhh[r * 64 + i];
        }
    } else if (b < 15078) {
        // gru/e2b MFMA B-operand packs (same lane layout as conv pack, verified r6)
        int idx = (b - 14966) * 256 + tid;       // [0, 28672)
        if (idx < 12288) {
            int j = idx & 7, lane = (idx >> 3) & 63, kt = (idx >> 9) & 1, ct = idx >> 10;
            int k = kt * 32 + ((lane >> 4) << 3) + j;
            int n = ct * 16 + (lane & 15);
            float v = gWih[n * 64 + k];
            unsigned short hi = f2bf(v);
            gWihP[idx] = hi;
            gWihP[12288 + idx] = f2bf(v - bf2f(hi));
        } else if (idx < 24576) {
            int i2 = idx - 12288;
            int j = i2 & 7, lane = (i2 >> 3) & 63, kt = (i2 >> 9) & 1, ct = i2 >> 10;
            int k = kt * 32 + ((lane >> 4) << 3) + j;
            int n = ct * 16 + (lane & 15);
            float v = gWhh[n * 64 + k];
            unsigned short hi = f2bf(v);
            gWhhP[i2] = hi;
            gWhhP[12288 + i2] = f2bf(v - bf2f(hi));
        } else {
            int i2 = idx - 24576;                // [0,4096)
            int j = i2 & 7, lane = (i2 >> 3) & 63, kt = (i2 >> 9) & 1, ct = i2 >> 10;
            int k = kt * 32 + ((lane >> 4) << 3) + j;
            int n = ct * 16 + (lane & 15);
            float v = e2b[k * 64 + n];
            unsigned short hi = f2bf(v);
            e2bP[i2] = hi;
            e2bP[4096 + i2] = f2bf(v - bf2f(hi));
        }
    } else {
        int n = (b - 15078) * 256 + tid;
        if (n < N_NODES) {
            int bb = batch[n];
            int pb = (n == 0) ? -1 : batch[n - 1];
            for (int g = pb + 1; g <= bb; ++g) gptr[g] = n;
            if (n == N_NODES - 1)
                for (int g = bb + 1; g <= N_GRAPHS; ++g) gptr[g] = N_NODES;
        }
    }
}

// ---------------- fused conv: MFMA phase A + flat message scatter (r6, unchanged) ----
__global__ __launch_bounds__(256, 4)
void conv_kernel(const float* __restrict__ node_h, const float* __restrict__ h1,
                 const unsigned short* __restrict__ Bhi, const unsigned short* __restrict__ Blo,
                 const float* __restrict__ Tb_g,
                 const int* __restrict__ tptr, const int* __restrict__ edge_list,
                 const int* __restrict__ src, const int* __restrict__ dst,
                 float* __restrict__ agg) {
    __shared__ float A_s[16][68];
    __shared__ float Tb_s[16][8];
    __shared__ float T_lds[16 * 544];    // [node]*544 + [fi]*68 + kk
    int bid = blockIdx.x;
    int nt = bid >> 3, ft = bid & 7;
    int n0 = nt * 16;
    int tid = threadIdx.x;

    {   // stage A-tile (fp32)
        int nn = tid >> 4, d4 = (tid & 15) * 4;
        int n = n0 + nn;
        float4 v = make_float4(0.f, 0.f, 0.f, 0.f);
        if (n < N_NODES) v = *(const float4*)(node_h + (size_t)n * 64 + d4);
        *(float4*)(&A_s[nn][d4]) = v;
    }
    if (tid < 128) {
        int nn = tid >> 3, fi = tid & 7;
        int n = n0 + nn;
        Tb_s[nn][fi] = (n < N_NODES) ? Tb_g[(size_t)n * 64 + ft * 8 + fi] : 0.f;
    }
    __syncthreads();

    int lane = tid & 63, wave = tid >> 6;
    int quad = lane >> 4, m = lane & 15;

    bf16x8 ahi[2], alo[2];
    #pragma unroll
    for (int kt = 0; kt < 2; ++kt) {
        const float* ap = &A_s[m][kt * 32 + quad * 8];
        float4 x0 = *(const float4*)ap;
        float4 x1 = *(const float4*)(ap + 4);
        float av[8] = {x0.x, x0.y, x0.z, x0.w, x1.x, x1.y, x1.z, x1.w};
        #pragma unroll
        for (int j = 0; j < 8; ++j) {
            unsigned short hi = f2bf(av[j]);
            ahi[kt][j] = (short)hi;
            alo[kt][j] = (short)f2bf(av[j] - bf2f(hi));
        }
    }

    int c0 = ft * 32;
    #pragma unroll 1
    for (int ci = 0; ci < 8; ++ci) {
        int ct = wave * 8 + ci;
        f32x4 acc = {0.f, 0.f, 0.f, 0.f};
        #pragma unroll
        for (int kt = 0; kt < 2; ++kt) {
            size_t base = ((size_t)((c0 + ct) * 2 + kt) * 64 + lane) * 8;
            bf16x8 bh = *(const bf16x8*)(Bhi + base);
            bf16x8 bl = *(const bf16x8*)(Blo + base);
            acc = __builtin_amdgcn_mfma_f32_16x16x32_bf16(ahi[kt], bh, acc, 0, 0, 0);
            acc = __builtin_amdgcn_mfma_f32_16x16x32_bf16(alo[kt], bh, acc, 0, 0, 0);
            acc = __builtin_amdgcn_mfma_f32_16x16x32_bf16(ahi[kt], bl, acc, 0, 0, 0);
            acc = __builtin_amdgcn_mfma_f32_16x16x32_bf16(alo[kt], bl, acc, 0, 0, 0);
        }
        int c = ct * 16 + m;
        int kk = c >> 3, fi = c & 7;
        #pragma unroll
        for (int r = 0; r < 4; ++r)
            T_lds[(quad * 4 + r) * 544 + fi * 68 + kk] = acc[r];
    }
    __syncthreads();

    int fi = tid & 7, slot = tid >> 3;
    int te0 = tptr[nt], te1 = tptr[nt + 1];
    for (int c = te0 + slot; c < te1; c += 32) {
        int e = edge_list[c];
        int nn = src[e] - n0;
        const float* h1e = h1 + (size_t)e * 64;
        const float* Tr = &T_lds[nn * 544 + fi * 68];
        float s = Tb_s[nn][fi];
        #pragma unroll
        for (int k4 = 0; k4 < 64; k4 += 4) {
            float4 h4 = *(const float4*)(h1e + k4);
            float4 tv = *(const float4*)(Tr + k4);
            s += h4.x * tv.x + h4.y * tv.y + h4.z * tv.z + h4.w * tv.w;
        }
        atomicAdd(&agg[(size_t)dst[e] * 64 + ft * 8 + fi], s);
    }
}

// ---------------- GRU as MFMA GEMM: 64 nodes/block, fused epilogue + Tb GEMM ------
// gi = m@WihT, gh = h@WhhT via bf16-split (3 products). Wave w owns f-range
// [w*16, w*16+16) across all 3 gates -> epilogue is pure-register. Then
// Tb = hn@e2b as a second chained MFMA GEMM. Re-zeroes agg (stream-ordered).
__global__ __launch_bounds__(256, 2)
void gru_kernel(float* __restrict__ node_h, float* __restrict__ agg,
                const float* __restrict__ deg, const float* __restrict__ conv_b,
                const unsigned short* __restrict__ WihP, const unsigned short* __restrict__ WhhP,
                const float* __restrict__ bih, const float* __restrict__ bhh,
                const unsigned short* __restrict__ e2bP,
                float* __restrict__ Tb_g, int want_tb) {
    __shared__ unsigned short m_bf[2][64][72];   // [hi/lo][node][d], stride 72 (16B-align, 2-way banks)
    __shared__ unsigned short h_bf[2][64][72];
    __shared__ unsigned short hn_bf[2][64][72];
    __shared__ float h_s[64][68];
    int n0 = blockIdx.x * 64;
    int tid = threadIdx.x;
    int lane = tid & 63, w = tid >> 6;
    int quad = lane >> 4, m16 = lane & 15;

    // stage m,h + bf16 split (agg re-zeroed for next conv iteration)
    for (int i = tid; i < 4096; i += 256) {
        int c = i >> 6, f = i & 63;
        int n = n0 + c;
        float mv = 0.f, hv = 0.f;
        if (n < N_NODES) {
            float dg = fmaxf(deg[n], 1.f);
            mv = fmaxf(agg[(size_t)n * 64 + f] / dg + conv_b[f], 0.f);
            agg[(size_t)n * 64 + f] = 0.f;
            hv = node_h[(size_t)n * 64 + f];
        }
        unsigned short mh = f2bf(mv);
        m_bf[0][c][f] = mh; m_bf[1][c][f] = f2bf(mv - bf2f(mh));
        unsigned short hh = f2bf(hv);
        h_bf[0][c][f] = hh; h_bf[1][c][f] = f2bf(hv - bf2f(hh));
        h_s[c][f] = hv;
    }

    // B-fragments (global, L1-hot): [gate][kt][hi/lo]
    bf16x8 Bi[3][2][2], Bh[3][2][2];
    #pragma unroll
    for (int g = 0; g < 3; ++g)
        #pragma unroll
        for (int kt = 0; kt < 2; ++kt) {
            size_t base = ((size_t)((g * 4 + w) * 2 + kt) * 64 + lane) * 8;
            Bi[g][kt][0] = *(const bf16x8*)(WihP + base);
            Bi[g][kt][1] = *(const bf16x8*)(WihP + 12288 + base);
            Bh[g][kt][0] = *(const bf16x8*)(WhhP + base);
            Bh[g][kt][1] = *(const bf16x8*)(WhhP + 12288 + base);
        }
    int f = w * 16 + m16;
    float br_i = bih[f],       br_h = bhh[f];
    float bz_i = bih[64 + f],  bz_h = bhh[64 + f];
    float bn_i = bih[128 + f], bn_h = bhh[128 + f];
    __syncthreads();

    #pragma unroll 1
    for (int mt = 0; mt < 4; ++mt) {
        bf16x8 Am[2][2], Ah[2][2];   // [kt][hi/lo]
        #pragma unroll
        for (int kt = 0; kt < 2; ++kt) {
            Am[kt][0] = *(const bf16x8*)(&m_bf[0][mt * 16 + m16][kt * 32 + quad * 8]);
            Am[kt][1] = *(const bf16x8*)(&m_bf[1][mt * 16 + m16][kt * 32 + quad * 8]);
            Ah[kt][0] = *(const bf16x8*)(&h_bf[0][mt * 16 + m16][kt * 32 + quad * 8]);
            Ah[kt][1] = *(const bf16x8*)(&h_bf[1][mt * 16 + m16][kt * 32 + quad * 8]);
        }
        f32x4 ai[3], ah[3];
        #pragma unroll
        for (int g = 0; g < 3; ++g) { ai[g] = (f32x4){0.f,0.f,0.f,0.f}; ah[g] = (f32x4){0.f,0.f,0.f,0.f}; }
        #pragma unroll
        for (int g = 0; g < 3; ++g)
            #pragma unroll
            for (int kt = 0; kt < 2; ++kt) {
                ai[g] = __builtin_amdgcn_mfma_f32_16x16x32_bf16(Am[kt][0], Bi[g][kt][0], ai[g], 0, 0, 0);
                ai[g] = __builtin_amdgcn_mfma_f32_16x16x32_bf16(Am[kt][0], Bi[g][kt][1], ai[g], 0, 0, 0);
                ai[g] = __builtin_amdgcn_mfma_f32_16x16x32_bf16(Am[kt][1], Bi[g][kt][0], ai[g], 0, 0, 0);
                ah[g] = __builtin_amdgcn_mfma_f32_16x16x32_bf16(Ah[kt][0], Bh[g][kt][0], ah[g], 0, 0, 0);
                ah[g] = __builtin_amdgcn_mfma_f32_16x16x32_bf16(Ah[kt][0], Bh[g][kt][1], ah[g], 0, 0, 0);
                ah[g] = __builtin_amdgcn_mfma_f32_16x16x32_bf16(Ah[kt][1], Bh[g][kt][0], ah[g], 0, 0, 0);
            }
        // epilogue: D row = quad*4+r (node), col = m16 (f within wave's range)
        #pragma unroll
        for (int r = 0; r < 4; ++r) {
            int node = mt * 16 + quad * 4 + r;
            float rr = sigmoidf_(ai[0][r] + br_i + ah[0][r] + br_h);
            float zz = sigmoidf_(ai[1][r] + bz_i + ah[1][r] + bz_h);
            float n2 = tanhf(ai[2][r] + bn_i + rr * (ah[2][r] + bn_h));
            float hnew = (1.f - zz) * n2 + zz * h_s[node][f];
            int n = n0 + node;
            if (n < N_NODES) node_h[(size_t)n * 64 + f] = hnew;
            unsigned short hh = f2bf(hnew);
            hn_bf[0][node][f] = hh;
            hn_bf[1][node][f] = f2bf(hnew - bf2f(hh));
        }
    }
    if (want_tb) {
        __syncthreads();
        bf16x8 Eb[2][2];
        #pragma unroll
        for (int kt = 0; kt < 2; ++kt) {
            size_t base = ((size_t)((w * 2 + kt) * 64) + lane) * 8;
            Eb[kt][0] = *(const bf16x8*)(e2bP + base);
            Eb[kt][1] = *(const bf16x8*)(e2bP + 4096 + base);
        }
        #pragma unroll 1
        for (int mt = 0; mt < 4; ++mt) {
            bf16x8 A2[2][2];
            #pragma unroll
            for (int kt = 0; kt < 2; ++kt) {
                A2[kt][0] = *(const bf16x8*)(&hn_bf[0][mt * 16 + m16][kt * 32 + quad * 8]);
                A2[kt][1] = *(const bf16x8*)(&hn_bf[1][mt * 16 + m16][kt * 32 + quad * 8]);
            }
            f32x4 acc = {0.f, 0.f, 0.f, 0.f};
            #pragma unroll
            for (int kt = 0; kt < 2; ++kt) {
                acc = __builtin_amdgcn_mfma_f32_16x16x32_bf16(A2[kt][0], Eb[kt][0], acc, 0, 0, 0);
                acc = __builtin_amdgcn_mfma_f32_16x16x32_bf16(A2[kt][0], Eb[kt][1], acc, 0, 0, 0);
                acc = __builtin_amdgcn_mfma_f32_16x16x32_bf16(A2[kt][1], Eb[kt][0], acc, 0, 0, 0);
            }
            #pragma unroll
            for (int r = 0; r < 4; ++r) {
                int n = n0 + mt * 16 + quad * 4 + r;
                if (n < N_NODES) Tb_g[(size_t)n * 64 + f] = acc[r];
            }
        }
    }
}

// ---------------- Set2Set (all 3 steps) + output MLP, one block per graph ----------------
__global__ __launch_bounds__(64)
void s2s_kernel(const float* __restrict__ node_h, const int* __restrict__ gptr,
                const float* __restrict__ WihT, const float* __restrict__ WhhT,
                const float* __restrict__ bih, const float* __restrict__ bhh,
                const float* __restrict__ o1W, const float* __restrict__ o1b,
                const float* __restrict__ o2W, const float* __restrict__ o2b,
                float* __restrict__ z) {
    int g = blockIdx.x, t = threadIdx.x;
    __shared__ float qs[128], hs[64], q[64], wts[64];
    qs[t] = 0.f; qs[64 + t] = 0.f; hs[t] = 0.f;
    float c_t = 0.f;
    int nbeg = gptr[g], nend = gptr[g + 1];
    __syncthreads();
    for (int st = 0; st < 3; ++st) {
        float gv[4];
        #pragma unroll
        for (int gate = 0; gate < 4; ++gate) {
            int row = gate * 64 + t;
            float s = bih[row] + bhh[row];
            #pragma unroll 8
            for (int i = 0; i < 128; ++i) s += qs[i] * WihT[i * 256 + row];
            #pragma unroll 8
            for (int i = 0; i < 64; ++i) s += hs[i] * WhhT[i * 256 + row];
            gv[gate] = s;
        }
        float c = sigmoidf_(gv[1]) * c_t + sigmoidf_(gv[0]) * tanhf(gv[2]);
        float hn = sigmoidf_(gv[3]) * tanhf(c);
        c_t = c;
        __syncthreads();
        hs[t] = hn; q[t] = hn;
        __syncthreads();
        float rm = -INFINITY, rs = 0.f, racc = 0.f;
        for (int base = nbeg; base < nend; base += 64) {
            int n = base + t;
            float e = -INFINITY;
            if (n < nend) {
                float s = 0.f;
                #pragma unroll 8
                for (int f = 0; f < 64; ++f) s += node_h[(size_t)n * 64 + f] * q[f];
                e = s;
            }
            float cm = e;
            #pragma unroll
            for (int o = 32; o > 0; o >>= 1) cm = fmaxf(cm, __shfl_down(cm, o));
            cm = __shfl(cm, 0);
            float nm = fmaxf(rm, cm);
            float scale = (rm == -INFINITY) ? 0.f : expf(rm - nm);
            float wv = (n < nend) ? expf(e - nm) : 0.f;
            float cs = wv;
            #pragma unroll
            for (int o = 32; o > 0; o >>= 1) cs += __shfl_down(cs, o);
            cs = __shfl(cs, 0);
            wts[t] = wv;
            __syncthreads();
            float na = racc * scale;
            int cnt2 = min(64, nend - base);
            for (int l = 0; l < cnt2; ++l) na += wts[l] * node_h[(size_t)(base + l) * 64 + t];
            racc = na;
            rs = rs * scale + cs;
            rm = nm;
            __syncthreads();
        }
        float r = (nend > nbeg) ? racc / rs : 0.f;
        qs[t] = q[t];
        qs[64 + t] = r;
        __syncthreads();
    }
    float sA = o1b[t], sB = o1b[t + 64];
    #pragma unroll 8
    for (int i = 0; i < 128; ++i) {
        float qv = qs[i];
        sA += qv * o1W[i * 128 + t];
        sB += qv * o1W[i * 128 + t + 64];
    }
    float red = fmaxf(sA, 0.f) * o2W[t] + fmaxf(sB, 0.f) * o2W[t + 64];
    #pragma unroll
    for (int o = 32; o > 0; o >>= 1) red += __shfl_down(red, o);
    if (t == 0) z[g] = red + o2b[0];
}

extern "C" void kernel_launch(void* const* d_in, const int* in_sizes, int n_in,
                              void* d_out, int out_size, void* d_ws, size_t ws_size,
                              hipStream_t stream) {
    const float* x         = (const float*)d_in[0];
    const float* edge_attr = (const float*)d_in[1];
    const int*   ei        = (const int*)d_in[2];
    const int*   batch     = (const int*)d_in[3];
    const float* in_W      = (const float*)d_in[4];
    const float* in_b      = (const float*)d_in[5];
    const float* e1_W      = (const float*)d_in[6];
    const float* e1_b      = (const float*)d_in[7];
    const float* e2_W      = (const float*)d_in[8];
    const float* e2_b      = (const float*)d_in[9];
    const float* conv_b    = (const float*)d_in[10];
    const float* gWih      = (const float*)d_in[11];
    const float* gWhh      = (const float*)d_in[12];
    const float* gbih      = (const float*)d_in[13];
    const float* gbhh      = (const float*)d_in[14];
    const float* lWih      = (const float*)d_in[15];
    const float* lWhh      = (const float*)d_in[16];
    const float* lbih      = (const float*)d_in[17];
    const float* lbhh      = (const float*)d_in[18];
    const float* o1W       = (const float*)d_in[19];
    const float* o1b       = (const float*)d_in[20];
    const float* o2W       = (const float*)d_in[21];
    const float* o2b       = (const float*)d_in[22];
    const int* src = ei;
    const int* dst = ei + N_EDGES;
    float* z = (float*)d_out;

    char* ws = (char*)d_ws;
    size_t off = 0;
    auto alloc = [&](size_t bytes) {
        void* p = ws + off;
        off = (off + bytes + 255) & ~(size_t)255;
        return p;
    };
    float* node_h   = (float*)alloc((size_t)N_NODES * 64 * 4);
    float* agg      = (float*)alloc((size_t)N_NODES * 64 * 4);
    float* h1       = (float*)alloc((size_t)N_EDGES * 64 * 4);
    unsigned short* Bhi = (unsigned short*)alloc((size_t)262144 * 2);
    unsigned short* Blo = (unsigned short*)alloc((size_t)262144 * 2);
    float* Tb_g     = (float*)alloc((size_t)N_NODES * 64 * 4);
    float* lWihT    = (float*)alloc(128 * 256 * 4);
    float* lWhhT    = (float*)alloc(64 * 256 * 4);
    unsigned short* gWihP = (unsigned short*)alloc(24576 * 2);
    unsigned short* gWhhP = (unsigned short*)alloc(24576 * 2);
    unsigned short* e2bP  = (unsigned short*)alloc(8192 * 2);
    float* deg      = (float*)alloc(N_NODES * 4);       // deg,tcnt adjacent (one memset)
    int*   tcnt     = (int*)alloc((N_TILES + 2) * 4);
    int*   tcursor  = (int*)alloc((N_TILES + 2) * 4);
    int*   tptr     = (int*)alloc((N_TILES + 1) * 4);
    int*   edge_list= (int*)alloc(N_EDGES * 4);
    int*   gptr     = (int*)alloc((N_GRAPHS + 1) * 4);

    size_t degpad = ((size_t)N_NODES * 4 + 255) & ~(size_t)255;
    hipMemsetAsync(deg, 0, degpad + (N_TILES + 2) * 4, stream);   // deg + tcnt
    hipMemsetAsync(agg, 0, (size_t)N_NODES * 64 * 4, stream);     // once; gru re-zeroes

    count_kernel<<<(N_EDGES + 255) / 256, 256, 0, stream>>>(src, dst, tcnt, deg);
    tscan_kernel<<<1, 1024, 0, stream>>>(tcnt, tptr, tcursor);
    fill_kernel<<<(N_EDGES + 255) / 256, 256, 0, stream>>>(src, tcursor, edge_list);
    prep_kernel<<<15137, 256, 0, stream>>>(x, in_W, in_b, node_h, e2_b, Tb_g,
                                           edge_attr, e1_W, e1_b, h1,
                                           e2_W, Bhi, Blo,
                                           lWih, lWhh, gWih, gWhh,
                                           lWihT, lWhhT, gWihP, gWhhP, e2bP,
                                           batch, gptr);

    for (int it = 0; it < 3; ++it) {
        conv_kernel<<<N_TILES * 8, 256, 0, stream>>>(node_h, h1, Bhi, Blo, Tb_g,
                                                     tptr, edge_list, src, dst, agg);
        gru_kernel<<<235, 256, 0, stream>>>(node_h, agg, deg, conv_b,
                                            gWihP, gWhhP, gbih, gbhh,
                                            e2bP, Tb_g, (it < 2) ? 1 : 0);
    }
    s2s_kernel<<<N_GRAPHS, 64, 0, stream>>>(node_h, gptr, lWihT, lWhhT, lbih, lbhh,
                                            o1W, o1b, o2W, o2b, z);
}

// Round 8
// 456.026 us; speedup vs baseline: 2.2579x; 1.1825x over previous
//
#include <hip/hip_runtime.h>
#include <math.h>

#define N_NODES 15000
#define N_EDGES 40000
#define N_GRAPHS 750
#define N_TILES 938   // ceil(15000/16)

typedef __attribute__((ext_vector_type(8))) short bf16x8;
typedef __attribute__((ext_vector_type(4))) float f32x4;

__device__ __forceinline__ float sigmoidf_(float x) { return 1.f / (1.f + expf(-x)); }

// round-to-nearest-even fp32 -> bf16 bits
__device__ __forceinline__ unsigned short f2bf(float v) {
    unsigned u = __float_as_uint(v);
    unsigned r = (u + 0x7FFFu + ((u >> 16) & 1u)) >> 16;
    return (unsigned short)r;
}
__device__ __forceinline__ float bf2f(unsigned short b) {
    return __uint_as_float(((unsigned)b) << 16);
}

// ---------------- CSR prep ----------------
__global__ void count_kernel(const int* __restrict__ src, const int* __restrict__ dst,
                             int* __restrict__ tcnt, float* __restrict__ deg) {
    int e = blockIdx.x * 256 + threadIdx.x;
    if (e >= N_EDGES) return;
    atomicAdd(&tcnt[src[e] >> 4], 1);
    atomicAdd(&deg[dst[e]], 1.f);
}

__global__ void tscan_kernel(const int* __restrict__ tcnt, int* __restrict__ tptr,
                             int* __restrict__ cursor) {
    __shared__ int buf[1024];
    int t = threadIdx.x;
    int v = (t < N_TILES) ? tcnt[t] : 0;
    buf[t] = v;
    __syncthreads();
    for (int ofs = 1; ofs < 1024; ofs <<= 1) {
        int a = (t >= ofs) ? buf[t - ofs] : 0;
        __syncthreads();
        buf[t] += a;
        __syncthreads();
    }
    if (t < N_TILES) {
        int excl = buf[t] - v;
        tptr[t] = excl;
        cursor[t] = excl;
    }
    if (t == N_TILES - 1) tptr[N_TILES] = buf[t];
}

__global__ void fill_kernel(const int* __restrict__ src, int* __restrict__ cursor,
                            int* __restrict__ edge_list) {
    int e = blockIdx.x * 256 + threadIdx.x;
    if (e >= N_EDGES) return;
    int slot = atomicAdd(&cursor[src[e] >> 4], 1);
    edge_list[slot] = e;
}

// ---------------- fused prep mega-kernel (block-range partitioned) ----------------
__global__ __launch_bounds__(256)
void prep_kernel(const float* __restrict__ x, const float* __restrict__ in_W,
                 const float* __restrict__ in_b, float* __restrict__ node_h,
                 const float* __restrict__ e2b, float* __restrict__ Tb_g,
                 const float* __restrict__ ea, const float* __restrict__ e1_W,
                 const float* __restrict__ e1_b, float* __restrict__ h1,
                 const float* __restrict__ e2W,
                 unsigned short* __restrict__ Bhi, unsigned short* __restrict__ Blo,
                 const float* __restrict__ lWih, const float* __restrict__ lWhh,
                 const float* __restrict__ gWih, const float* __restrict__ gWhh,
                 float* __restrict__ lWihT, float* __restrict__ lWhhT,
                 unsigned short* __restrict__ gWihP, unsigned short* __restrict__ gWhhP,
                 unsigned short* __restrict__ e2bP,
                 const int* __restrict__ batch, int* __restrict__ gptr) {
    int b = blockIdx.x;
    int tid = threadIdx.x;
    if (b < 3750) {
        __shared__ float xs[4][32];
        __shared__ float hrow[4][64];
        int n0 = b * 4;
        if (tid < 128) xs[tid >> 5][tid & 31] = x[n0 * 32 + tid];
        __syncthreads();
        int nn = tid >> 6, f = tid & 63;
        float s = in_b[f];
        #pragma unroll
        for (int i = 0; i < 32; ++i) s += xs[nn][i] * in_W[i * 64 + f];
        s = fmaxf(s, 0.f);
        node_h[(size_t)(n0 + nn) * 64 + f] = s;
        hrow[nn][f] = s;
        __syncthreads();
        float t2 = 0.f;
        #pragma unroll 8
        for (int d = 0; d < 64; ++d) t2 += hrow[nn][d] * e2b[d * 64 + f];
        Tb_g[(size_t)(n0 + nn) * 64 + f] = t2;
    } else if (b < 13750) {
        __shared__ float eas[4][16];
        int e0 = (b - 3750) * 4;
        if (tid < 64) eas[tid >> 4][tid & 15] = ea[e0 * 16 + tid];
        __syncthreads();
        int nn = tid >> 6, f = tid & 63;
        float s = e1_b[f];
        #pragma unroll
        for (int i = 0; i < 16; ++i) s += eas[nn][i] * e1_W[i * 64 + f];
        h1[(size_t)(e0 + nn) * 64 + f] = fmaxf(s, 0.f);
    } else if (b < 14774) {
        // conv B pack: shorts base = (((ft*32+ct)*2+kt)*64 + lane)*8 + j
        int idx = (b - 13750) * 256 + tid;           // [0, 262144)
        int j = idx & 7, lane = (idx >> 3) & 63, kt = (idx >> 9) & 1;
        int ct = (idx >> 10) & 31, ft = idx >> 15;
        int d = kt * 32 + ((lane >> 4) << 3) + j;
        int c = ct * 16 + (lane & 15);
        int kk = c >> 3, fi = c & 7;
        float v = e2W[(size_t)kk * 4096 + d * 64 + ft * 8 + fi];
        unsigned short hi = f2bf(v);
        Bhi[idx] = hi;
        Blo[idx] = f2bf(v - bf2f(hi));
    } else if (b < 14966) {
        int idx = (b - 14774) * 256 + tid;
        if (idx < 32768) {                       // lWih [256][128] -> [128][256]
            int i = idx >> 8, r = idx & 255;
            lWihT[i * 256 + r] = lWih[r * 128 + i];
        } else if (idx < 49152) {                // lWhh [256][64] -> [64][256]
            int x2 = idx - 32768; int i = x2 >> 8, r = x2 & 255;
            lWhhT[i * 256 + r] = lWhh[r * 64 + i];
        }
    } else if (b < 15078) {
        // gru/e2b MFMA B-operand packs
        int idx = (b - 14966) * 256 + tid;       // [0, 28672)
        if (idx < 12288) {
            int j = idx & 7, lane = (idx >> 3) & 63, kt = (idx >> 9) & 1, ct = idx >> 10;
            int k = kt * 32 + ((lane >> 4) << 3) + j;
            int n = ct * 16 + (lane & 15);
            float v = gWih[n * 64 + k];
            unsigned short hi = f2bf(v);
            gWihP[idx] = hi;
            gWihP[12288 + idx] = f2bf(v - bf2f(hi));
        } else if (idx < 24576) {
            int i2 = idx - 12288;
            int j = i2 & 7, lane = (i2 >> 3) & 63, kt = (i2 >> 9) & 1, ct = i2 >> 10;
            int k = kt * 32 + ((lane >> 4) << 3) + j;
            int n = ct * 16 + (lane & 15);
            float v = gWhh[n * 64 + k];
            unsigned short hi = f2bf(v);
            gWhhP[i2] = hi;
            gWhhP[12288 + i2] = f2bf(v - bf2f(hi));
        } else {
            int i2 = idx - 24576;                // [0,4096)
            int j = i2 & 7, lane = (i2 >> 3) & 63, kt = (i2 >> 9) & 1, ct = i2 >> 10;
            int k = kt * 32 + ((lane >> 4) << 3) + j;
            int n = ct * 16 + (lane & 15);
            float v = e2b[k * 64 + n];
            unsigned short hi = f2bf(v);
            e2bP[i2] = hi;
            e2bP[4096 + i2] = f2bf(v - bf2f(hi));
        }
    } else {
        int n = (b - 15078) * 256 + tid;
        if (n < N_NODES) {
            int bb = batch[n];
            int pb = (n == 0) ? -1 : batch[n - 1];
            for (int g = pb + 1; g <= bb; ++g) gptr[g] = n;
            if (n == N_NODES - 1)
                for (int g = bb + 1; g <= N_GRAPHS; ++g) gptr[g] = N_NODES;
        }
    }
}

// ---------------- fused conv: MFMA phase A + flat message scatter ----------------
// Phase A: 3-product bf16 split (hi*hi + lo*hi + hi*lo), dual acc chains (per kt),
//          register prefetch of next ci's B-frags. Phase B: T node stride 552
//          (8 mod 32 banks -> nn spreads bank groups).
__global__ __launch_bounds__(256, 4)
void conv_kernel(const float* __restrict__ node_h, const float* __restrict__ h1,
                 const unsigned short* __restrict__ Bhi, const unsigned short* __restrict__ Blo,
                 const float* __restrict__ Tb_g,
                 const int* __restrict__ tptr, const int* __restrict__ edge_list,
                 const int* __restrict__ src, const int* __restrict__ dst,
                 float* __restrict__ agg) {
    __shared__ float A_s[16][68];
    __shared__ float Tb_s[16][8];
    __shared__ float T_lds[16 * 552];    // [node]*552 + [fi]*68 + kk ; 552%32=8
    int bid = blockIdx.x;
    int nt = bid >> 3, ft = bid & 7;
    int n0 = nt * 16;
    int tid = threadIdx.x;

    {   // stage A-tile (fp32)
        int nn = tid >> 4, d4 = (tid & 15) * 4;
        int n = n0 + nn;
        float4 v = make_float4(0.f, 0.f, 0.f, 0.f);
        if (n < N_NODES) v = *(const float4*)(node_h + (size_t)n * 64 + d4);
        *(float4*)(&A_s[nn][d4]) = v;
    }
    if (tid < 128) {
        int nn = tid >> 3, fi = tid & 7;
        int n = n0 + nn;
        Tb_s[nn][fi] = (n < N_NODES) ? Tb_g[(size_t)n * 64 + ft * 8 + fi] : 0.f;
    }
    __syncthreads();

    int lane = tid & 63, wave = tid >> 6;
    int quad = lane >> 4, m = lane & 15;

    bf16x8 ahi[2], alo[2];
    #pragma unroll
    for (int kt = 0; kt < 2; ++kt) {
        const float* ap = &A_s[m][kt * 32 + quad * 8];
        float4 x0 = *(const float4*)ap;
        float4 x1 = *(const float4*)(ap + 4);
        float av[8] = {x0.x, x0.y, x0.z, x0.w, x1.x, x1.y, x1.z, x1.w};
        #pragma unroll
        for (int j = 0; j < 8; ++j) {
            unsigned short hi = f2bf(av[j]);
            ahi[kt][j] = (short)hi;
            alo[kt][j] = (short)f2bf(av[j] - bf2f(hi));
        }
    }

    // B-frag pointers: ct stride = 1024 shorts, kt stride = 512 shorts
    size_t base0 = ((size_t)((ft * 32 + wave * 8) * 2) * 64 + lane) * 8;
    const unsigned short* ph = Bhi + base0;
    const unsigned short* pl = Blo + base0;
    bf16x8 bh0 = *(const bf16x8*)(ph);
    bf16x8 bh1 = *(const bf16x8*)(ph + 512);
    bf16x8 bl0 = *(const bf16x8*)(pl);
    bf16x8 bl1 = *(const bf16x8*)(pl + 512);

    #pragma unroll 1
    for (int ci = 0; ci < 8; ++ci) {
        bf16x8 ch0 = bh0, ch1 = bh1, cl0 = bl0, cl1 = bl1;
        if (ci < 7) {
            const unsigned short* nh = ph + (ci + 1) * 1024;
            const unsigned short* nl = pl + (ci + 1) * 1024;
            bh0 = *(const bf16x8*)(nh);
            bh1 = *(const bf16x8*)(nh + 512);
            bl0 = *(const bf16x8*)(nl);
            bl1 = *(const bf16x8*)(nl + 512);
        }
        f32x4 accA = {0.f, 0.f, 0.f, 0.f};
        f32x4 accB = {0.f, 0.f, 0.f, 0.f};
        accA = __builtin_amdgcn_mfma_f32_16x16x32_bf16(ahi[0], ch0, accA, 0, 0, 0);
        accB = __builtin_amdgcn_mfma_f32_16x16x32_bf16(ahi[1], ch1, accB, 0, 0, 0);
        accA = __builtin_amdgcn_mfma_f32_16x16x32_bf16(alo[0], ch0, accA, 0, 0, 0);
        accB = __builtin_amdgcn_mfma_f32_16x16x32_bf16(alo[1], ch1, accB, 0, 0, 0);
        accA = __builtin_amdgcn_mfma_f32_16x16x32_bf16(ahi[0], cl0, accA, 0, 0, 0);
        accB = __builtin_amdgcn_mfma_f32_16x16x32_bf16(ahi[1], cl1, accB, 0, 0, 0);
        int c = (wave * 8 + ci) * 16 + m;
        int kk = c >> 3, fi = c & 7;
        #pragma unroll
        for (int r = 0; r < 4; ++r)
            T_lds[(quad * 4 + r) * 552 + fi * 68 + kk] = accA[r] + accB[r];
    }
    __syncthreads();

    int fi = tid & 7, slot = tid >> 3;
    int te0 = tptr[nt], te1 = tptr[nt + 1];
    for (int c = te0 + slot; c < te1; c += 32) {
        int e = edge_list[c];
        int nn = src[e] - n0;
        const float* h1e = h1 + (size_t)e * 64;
        const float* Tr = &T_lds[nn * 552 + fi * 68];
        float s = Tb_s[nn][fi];
        #pragma unroll
        for (int k4 = 0; k4 < 64; k4 += 4) {
            float4 h4 = *(const float4*)(h1e + k4);
            float4 tv = *(const float4*)(Tr + k4);
            s += h4.x * tv.x + h4.y * tv.y + h4.z * tv.z + h4.w * tv.w;
        }
        atomicAdd(&agg[(size_t)dst[e] * 64 + ft * 8 + fi], s);
    }
}

// ---------------- GRU as MFMA GEMM (r7, unchanged) ----------------
__global__ __launch_bounds__(256, 2)
void gru_kernel(float* __restrict__ node_h, float* __restrict__ agg,
                const float* __restrict__ deg, const float* __restrict__ conv_b,
                const unsigned short* __restrict__ WihP, const unsigned short* __restrict__ WhhP,
                const float* __restrict__ bih, const float* __restrict__ bhh,
                const unsigned short* __restrict__ e2bP,
                float* __restrict__ Tb_g, int want_tb) {
    __shared__ unsigned short m_bf[2][64][72];
    __shared__ unsigned short h_bf[2][64][72];
    __shared__ unsigned short hn_bf[2][64][72];
    __shared__ float h_s[64][68];
    int n0 = blockIdx.x * 64;
    int tid = threadIdx.x;
    int lane = tid & 63, w = tid >> 6;
    int quad = lane >> 4, m16 = lane & 15;

    for (int i = tid; i < 4096; i += 256) {
        int c = i >> 6, f = i & 63;
        int n = n0 + c;
        float mv = 0.f, hv = 0.f;
        if (n < N_NODES) {
            float dg = fmaxf(deg[n], 1.f);
            mv = fmaxf(agg[(size_t)n * 64 + f] / dg + conv_b[f], 0.f);
            agg[(size_t)n * 64 + f] = 0.f;
            hv = node_h[(size_t)n * 64 + f];
        }
        unsigned short mh = f2bf(mv);
        m_bf[0][c][f] = mh; m_bf[1][c][f] = f2bf(mv - bf2f(mh));
        unsigned short hh = f2bf(hv);
        h_bf[0][c][f] = hh; h_bf[1][c][f] = f2bf(hv - bf2f(hh));
        h_s[c][f] = hv;
    }

    bf16x8 Bi[3][2][2], Bh[3][2][2];
    #pragma unroll
    for (int g = 0; g < 3; ++g)
        #pragma unroll
        for (int kt = 0; kt < 2; ++kt) {
            size_t base = ((size_t)((g * 4 + w) * 2 + kt) * 64 + lane) * 8;
            Bi[g][kt][0] = *(const bf16x8*)(WihP + base);
            Bi[g][kt][1] = *(const bf16x8*)(WihP + 12288 + base);
            Bh[g][kt][0] = *(const bf16x8*)(WhhP + base);
            Bh[g][kt][1] = *(const bf16x8*)(WhhP + 12288 + base);
        }
    int f = w * 16 + m16;
    float br_i = bih[f],       br_h = bhh[f];
    float bz_i = bih[64 + f],  bz_h = bhh[64 + f];
    float bn_i = bih[128 + f], bn_h = bhh[128 + f];
    __syncthreads();

    #pragma unroll 1
    for (int mt = 0; mt < 4; ++mt) {
        bf16x8 Am[2][2], Ah[2][2];
        #pragma unroll
        for (int kt = 0; kt < 2; ++kt) {
            Am[kt][0] = *(const bf16x8*)(&m_bf[0][mt * 16 + m16][kt * 32 + quad * 8]);
            Am[kt][1] = *(const bf16x8*)(&m_bf[1][mt * 16 + m16][kt * 32 + quad * 8]);
            Ah[kt][0] = *(const bf16x8*)(&h_bf[0][mt * 16 + m16][kt * 32 + quad * 8]);
            Ah[kt][1] = *(const bf16x8*)(&h_bf[1][mt * 16 + m16][kt * 32 + quad * 8]);
        }
        f32x4 ai[3], ah[3];
        #pragma unroll
        for (int g = 0; g < 3; ++g) { ai[g] = (f32x4){0.f,0.f,0.f,0.f}; ah[g] = (f32x4){0.f,0.f,0.f,0.f}; }
        #pragma unroll
        for (int g = 0; g < 3; ++g)
            #pragma unroll
            for (int kt = 0; kt < 2; ++kt) {
                ai[g] = __builtin_amdgcn_mfma_f32_16x16x32_bf16(Am[kt][0], Bi[g][kt][0], ai[g], 0, 0, 0);
                ai[g] = __builtin_amdgcn_mfma_f32_16x16x32_bf16(Am[kt][0], Bi[g][kt][1], ai[g], 0, 0, 0);
                ai[g] = __builtin_amdgcn_mfma_f32_16x16x32_bf16(Am[kt][1], Bi[g][kt][0], ai[g], 0, 0, 0);
                ah[g] = __builtin_amdgcn_mfma_f32_16x16x32_bf16(Ah[kt][0], Bh[g][kt][0], ah[g], 0, 0, 0);
                ah[g] = __builtin_amdgcn_mfma_f32_16x16x32_bf16(Ah[kt][0], Bh[g][kt][1], ah[g], 0, 0, 0);
                ah[g] = __builtin_amdgcn_mfma_f32_16x16x32_bf16(Ah[kt][1], Bh[g][kt][0], ah[g], 0, 0, 0);
            }
        #pragma unroll
        for (int r = 0; r < 4; ++r) {
            int node = mt * 16 + quad * 4 + r;
            float rr = sigmoidf_(ai[0][r] + br_i + ah[0][r] + br_h);
            float zz = sigmoidf_(ai[1][r] + bz_i + ah[1][r] + bz_h);
            float n2 = tanhf(ai[2][r] + bn_i + rr * (ah[2][r] + bn_h));
            float hnew = (1.f - zz) * n2 + zz * h_s[node][f];
            int n = n0 + node;
            if (n < N_NODES) node_h[(size_t)n * 64 + f] = hnew;
            unsigned short hh = f2bf(hnew);
            hn_bf[0][node][f] = hh;
            hn_bf[1][node][f] = f2bf(hnew - bf2f(hh));
        }
    }
    if (want_tb) {
        __syncthreads();
        bf16x8 Eb[2][2];
        #pragma unroll
        for (int kt = 0; kt < 2; ++kt) {
            size_t base = ((size_t)((w * 2 + kt) * 64) + lane) * 8;
            Eb[kt][0] = *(const bf16x8*)(e2bP + base);
            Eb[kt][1] = *(const bf16x8*)(e2bP + 4096 + base);
        }
        #pragma unroll 1
        for (int mt = 0; mt < 4; ++mt) {
            bf16x8 A2[2][2];
            #pragma unroll
            for (int kt = 0; kt < 2; ++kt) {
                A2[kt][0] = *(const bf16x8*)(&hn_bf[0][mt * 16 + m16][kt * 32 + quad * 8]);
                A2[kt][1] = *(const bf16x8*)(&hn_bf[1][mt * 16 + m16][kt * 32 + quad * 8]);
            }
            f32x4 acc = {0.f, 0.f, 0.f, 0.f};
            #pragma unroll
            for (int kt = 0; kt < 2; ++kt) {
                acc = __builtin_amdgcn_mfma_f32_16x16x32_bf16(A2[kt][0], Eb[kt][0], acc, 0, 0, 0);
                acc = __builtin_amdgcn_mfma_f32_16x16x32_bf16(A2[kt][0], Eb[kt][1], acc, 0, 0, 0);
                acc = __builtin_amdgcn_mfma_f32_16x16x32_bf16(A2[kt][1], Eb[kt][0], acc, 0, 0, 0);
            }
            #pragma unroll
            for (int r = 0; r < 4; ++r) {
                int n = n0 + mt * 16 + quad * 4 + r;
                if (n < N_NODES) Tb_g[(size_t)n * 64 + f] = acc[r];
            }
        }
    }
}

// ---------------- Set2Set (3 steps) + output MLP, 128 threads (2 waves) per graph ---
__global__ __launch_bounds__(128)
void s2s_kernel(const float* __restrict__ node_h, const int* __restrict__ gptr,
                const float* __restrict__ WihT, const float* __restrict__ WhhT,
                const float* __restrict__ bih, const float* __restrict__ bhh,
                const float* __restrict__ o1W, const float* __restrict__ o1b,
                const float* __restrict__ o2W, const float* __restrict__ o2b,
                float* __restrict__ z) {
    int g = blockIdx.x, tid = threadIdx.x;
    int f = tid & 63, half = tid >> 6;
    __shared__ float qs[128], hs[64], q[64], wts[128], gvs[4][64], racc_s[2][64];
    __shared__ float mred[2], sred[2], ored[2];
    if (half == 0) { qs[f] = 0.f; qs[64 + f] = 0.f; hs[f] = 0.f; }
    float c_t = 0.f;
    int nbeg = gptr[g], nend = gptr[g + 1];
    __syncthreads();
    for (int st = 0; st < 3; ++st) {
        // gates: 2 per thread (half picks pair)
        #pragma unroll
        for (int gg = 0; gg < 2; ++gg) {
            int gate = half * 2 + gg;
            int row = gate * 64 + f;
            float s = bih[row] + bhh[row];
            #pragma unroll 8
            for (int i = 0; i < 128; ++i) s += qs[i] * WihT[i * 256 + row];
            #pragma unroll 8
            for (int i = 0; i < 64; ++i) s += hs[i] * WhhT[i * 256 + row];
            gvs[gate][f] = s;
        }
        __syncthreads();
        if (half == 0) {
            float c = sigmoidf_(gvs[1][f]) * c_t + sigmoidf_(gvs[0][f]) * tanhf(gvs[2][f]);
            float hn = sigmoidf_(gvs[3][f]) * tanhf(c);
            c_t = c;
            hs[f] = hn; q[f] = hn;
        }
        __syncthreads();
        float rm = -INFINITY, rs = 0.f, raccl = 0.f;
        for (int base = nbeg; base < nend; base += 128) {
            int n = base + tid;
            float e = -INFINITY;
            if (n < nend) {
                float s = 0.f;
                #pragma unroll 8
                for (int ff = 0; ff < 64; ++ff) s += node_h[(size_t)n * 64 + ff] * q[ff];
                e = s;
            }
            float cm = e;
            #pragma unroll
            for (int o = 32; o > 0; o >>= 1) cm = fmaxf(cm, __shfl_down(cm, o));
            if ((tid & 63) == 0) mred[half] = cm;
            __syncthreads();
            float bm = fmaxf(mred[0], mred[1]);
            float nm = fmaxf(rm, bm);
            float scale = (rm == -INFINITY) ? 0.f : expf(rm - nm);
            float wv = (n < nend) ? expf(e - nm) : 0.f;
            wts[tid] = wv;
            float cs = wv;
            #pragma unroll
            for (int o = 32; o > 0; o >>= 1) cs += __shfl_down(cs, o);
            if ((tid & 63) == 0) sred[half] = cs;
            __syncthreads();
            float bs = sred[0] + sred[1];
            float na = raccl * scale;
            int cnt2 = min(128, nend - base);
            int l0 = half * 64, l1 = min(l0 + 64, cnt2);
            for (int l = l0; l < l1; ++l) na += wts[l] * node_h[(size_t)(base + l) * 64 + f];
            raccl = na;
            rs = rs * scale + bs;
            rm = nm;
            __syncthreads();
        }
        racc_s[half][f] = raccl;
        __syncthreads();
        if (half == 0) {
            float r = (nend > nbeg) ? (racc_s[0][f] + racc_s[1][f]) / rs : 0.f;
            qs[f] = q[f];
            qs[64 + f] = r;
        }
        __syncthreads();
    }
    // output MLP: 128 threads, one row each
    float sA = o1b[tid];
    #pragma unroll 8
    for (int i = 0; i < 128; ++i) sA += qs[i] * o1W[i * 128 + tid];
    float red = fmaxf(sA, 0.f) * o2W[tid];
    #pragma unroll
    for (int o = 32; o > 0; o >>= 1) red += __shfl_down(red, o);
    if ((tid & 63) == 0) ored[half] = red;
    __syncthreads();
    if (tid == 0) z[g] = ored[0] + ored[1] + o2b[0];
}

extern "C" void kernel_launch(void* const* d_in, const int* in_sizes, int n_in,
                              void* d_out, int out_size, void* d_ws, size_t ws_size,
                              hipStream_t stream) {
    const float* x         = (const float*)d_in[0];
    const float* edge_attr = (const float*)d_in[1];
    const int*   ei        = (const int*)d_in[2];
    const int*   batch     = (const int*)d_in[3];
    const float* in_W      = (const float*)d_in[4];
    const float* in_b      = (const float*)d_in[5];
    const float* e1_W      = (const float*)d_in[6];
    const float* e1_b      = (const float*)d_in[7];
    const float* e2_W      = (const float*)d_in[8];
    const float* e2_b      = (const float*)d_in[9];
    const float* conv_b    = (const float*)d_in[10];
    const float* gWih      = (const float*)d_in[11];
    const float* gWhh      = (const float*)d_in[12];
    const float* gbih      = (const float*)d_in[13];
    const float* gbhh      = (const float*)d_in[14];
    const float* lWih      = (const float*)d_in[15];
    const float* lWhh      = (const float*)d_in[16];
    const float* lbih      = (const float*)d_in[17];
    const float* lbhh      = (const float*)d_in[18];
    const float* o1W       = (const float*)d_in[19];
    const float* o1b       = (const float*)d_in[20];
    const float* o2W       = (const float*)d_in[21];
    const float* o2b       = (const float*)d_in[22];
    const int* src = ei;
    const int* dst = ei + N_EDGES;
    float* z = (float*)d_out;

    char* ws = (char*)d_ws;
    size_t off = 0;
    auto alloc = [&](size_t bytes) {
        void* p = ws + off;
        off = (off + bytes + 255) & ~(size_t)255;
        return p;
    };
    float* node_h   = (float*)alloc((size_t)N_NODES * 64 * 4);
    float* agg      = (float*)alloc((size_t)N_NODES * 64 * 4);
    float* h1       = (float*)alloc((size_t)N_EDGES * 64 * 4);
    unsigned short* Bhi = (unsigned short*)alloc((size_t)262144 * 2);
    unsigned short* Blo = (unsigned short*)alloc((size_t)262144 * 2);
    float* Tb_g     = (float*)alloc((size_t)N_NODES * 64 * 4);
    float* lWihT    = (float*)alloc(128 * 256 * 4);
    float* lWhhT    = (float*)alloc(64 * 256 * 4);
    unsigned short* gWihP = (unsigned short*)alloc(24576 * 2);
    unsigned short* gWhhP = (unsigned short*)alloc(24576 * 2);
    unsigned short* e2bP  = (unsigned short*)alloc(8192 * 2);
    float* deg      = (float*)alloc(N_NODES * 4);       // deg,tcnt adjacent (one memset)
    int*   tcnt     = (int*)alloc((N_TILES + 2) * 4);
    int*   tcursor  = (int*)alloc((N_TILES + 2) * 4);
    int*   tptr     = (int*)alloc((N_TILES + 1) * 4);
    int*   edge_list= (int*)alloc(N_EDGES * 4);
    int*   gptr     = (int*)alloc((N_GRAPHS + 1) * 4);

    size_t degpad = ((size_t)N_NODES * 4 + 255) & ~(size_t)255;
    hipMemsetAsync(deg, 0, degpad + (N_TILES + 2) * 4, stream);   // deg + tcnt
    hipMemsetAsync(agg, 0, (size_t)N_NODES * 64 * 4, stream);     // once; gru re-zeroes

    count_kernel<<<(N_EDGES + 255) / 256, 256, 0, stream>>>(src, dst, tcnt, deg);
    tscan_kernel<<<1, 1024, 0, stream>>>(tcnt, tptr, tcursor);
    fill_kernel<<<(N_EDGES + 255) / 256, 256, 0, stream>>>(src, tcursor, edge_list);
    prep_kernel<<<15137, 256, 0, stream>>>(x, in_W, in_b, node_h, e2_b, Tb_g,
                                           edge_attr, e1_W, e1_b, h1,
                                           e2_W, Bhi, Blo,
                                           lWih, lWhh, gWih, gWhh,
                                           lWihT, lWhhT, gWihP, gWhhP, e2bP,
                                           batch, gptr);

    for (int it = 0; it < 3; ++it) {
        conv_kernel<<<N_TILES * 8, 256, 0, stream>>>(node_h, h1, Bhi, Blo, Tb_g,
                                                     tptr, edge_list, src, dst, agg);
        gru_kernel<<<235, 256, 0, stream>>>(node_h, agg, deg, conv_b,
                                            gWihP, gWhhP, gbih, gbhh,
                                            e2bP, Tb_g, (it < 2) ? 1 : 0);
    }
    s2s_kernel<<<N_GRAPHS, 128, 0, stream>>>(node_h, gptr, lWihT, lWhhT, lbih, lbhh,
                                             o1W, o1b, o2W, o2b, z);
}

// Round 9
// 444.088 us; speedup vs baseline: 2.3186x; 1.0269x over previous
//
#include <hip/hip_runtime.h>
#include <math.h>

#define N_NODES 15000
#define N_EDGES 40000
#define N_GRAPHS 750
#define N_TILES 938    // ceil(15000/16)
#define N_TILES_PAD 944  // multiple of 8 -> ft-sibling blocks share XCD under round-robin

typedef __attribute__((ext_vector_type(8))) short bf16x8;
typedef __attribute__((ext_vector_type(4))) float f32x4;

__device__ __forceinline__ float sigmoidf_(float x) { return 1.f / (1.f + expf(-x)); }

// round-to-nearest-even fp32 -> bf16 bits
__device__ __forceinline__ unsigned short f2bf(float v) {
    unsigned u = __float_as_uint(v);
    unsigned r = (u + 0x7FFFu + ((u >> 16) & 1u)) >> 16;
    return (unsigned short)r;
}
__device__ __forceinline__ float bf2f(unsigned short b) {
    return __uint_as_float(((unsigned)b) << 16);
}

// ---------------- CSR scan/fill ----------------
__global__ void tscan_kernel(const int* __restrict__ tcnt, int* __restrict__ tptr,
                             int* __restrict__ cursor) {
    __shared__ int buf[1024];
    int t = threadIdx.x;
    int v = (t < N_TILES) ? tcnt[t] : 0;
    buf[t] = v;
    __syncthreads();
    for (int ofs = 1; ofs < 1024; ofs <<= 1) {
        int a = (t >= ofs) ? buf[t - ofs] : 0;
        __syncthreads();
        buf[t] += a;
        __syncthreads();
    }
    int excl = buf[t] - v;
    if (t <= N_TILES_PAD) tptr[t] = excl;   // t>=938 -> excl == total
    if (t < N_TILES) cursor[t] = excl;
}

__global__ void fill_kernel(const int* __restrict__ src, int* __restrict__ cursor,
                            int* __restrict__ edge_list) {
    int e = blockIdx.x * 256 + threadIdx.x;
    if (e >= N_EDGES) return;
    int slot = atomicAdd(&cursor[src[e] >> 4], 1);
    edge_list[slot] = e;
}

// ---------------- fused prep mega-kernel (block-range partitioned) ----------------
// [0,3750): proj + initial Tb. [3750,13750): h1. [13750,14774): conv e2_W bf16 pack.
// [14774,14966): LSTM transposes. [14966,15078): gru/e2b packs. [15078,15137): gptr.
// [15137,15294): edge count (tcnt/deg).
__global__ __launch_bounds__(256)
void prep_kernel(const float* __restrict__ x, const float* __restrict__ in_W,
                 const float* __restrict__ in_b, float* __restrict__ node_h,
                 const float* __restrict__ e2b, float* __restrict__ Tb_g,
                 const float* __restrict__ ea, const float* __restrict__ e1_W,
                 const float* __restrict__ e1_b, float* __restrict__ h1,
                 const float* __restrict__ e2W,
                 unsigned short* __restrict__ Bhi, unsigned short* __restrict__ Blo,
                 const float* __restrict__ lWih, const float* __restrict__ lWhh,
                 const float* __restrict__ gWih, const float* __restrict__ gWhh,
                 float* __restrict__ lWihT, float* __restrict__ lWhhT,
                 unsigned short* __restrict__ gWihP, unsigned short* __restrict__ gWhhP,
                 unsigned short* __restrict__ e2bP,
                 const int* __restrict__ batch, int* __restrict__ gptr,
                 const int* __restrict__ src, const int* __restrict__ dst,
                 int* __restrict__ tcnt, float* __restrict__ deg) {
    int b = blockIdx.x;
    int tid = threadIdx.x;
    if (b < 3750) {
        __shared__ float xs[4][32];
        __shared__ float hrow[4][64];
        int n0 = b * 4;
        if (tid < 128) xs[tid >> 5][tid & 31] = x[n0 * 32 + tid];
        __syncthreads();
        int nn = tid >> 6, f = tid & 63;
        float s = in_b[f];
        #pragma unroll
        for (int i = 0; i < 32; ++i) s += xs[nn][i] * in_W[i * 64 + f];
        s = fmaxf(s, 0.f);
        node_h[(size_t)(n0 + nn) * 64 + f] = s;
        hrow[nn][f] = s;
        __syncthreads();
        float t2 = 0.f;
        #pragma unroll 8
        for (int d = 0; d < 64; ++d) t2 += hrow[nn][d] * e2b[d * 64 + f];
        Tb_g[(size_t)(n0 + nn) * 64 + f] = t2;
    } else if (b < 13750) {
        __shared__ float eas[4][16];
        int e0 = (b - 3750) * 4;
        if (tid < 64) eas[tid >> 4][tid & 15] = ea[e0 * 16 + tid];
        __syncthreads();
        int nn = tid >> 6, f = tid & 63;
        float s = e1_b[f];
        #pragma unroll
        for (int i = 0; i < 16; ++i) s += eas[nn][i] * e1_W[i * 64 + f];
        h1[(size_t)(e0 + nn) * 64 + f] = fmaxf(s, 0.f);
    } else if (b < 14774) {
        // conv B pack: shorts base = (((ft*32+ct)*2+kt)*64 + lane)*8 + j
        int idx = (b - 13750) * 256 + tid;           // [0, 262144)
        int j = idx & 7, lane = (idx >> 3) & 63, kt = (idx >> 9) & 1;
        int ct = (idx >> 10) & 31, ft = idx >> 15;
        int d = kt * 32 + ((lane >> 4) << 3) + j;
        int c = ct * 16 + (lane & 15);
        int kk = c >> 3, fi = c & 7;
        float v = e2W[(size_t)kk * 4096 + d * 64 + ft * 8 + fi];
        unsigned short hi = f2bf(v);
        Bhi[idx] = hi;
        Blo[idx] = f2bf(v - bf2f(hi));
    } else if (b < 14966) {
        int idx = (b - 14774) * 256 + tid;
        if (idx < 32768) {                       // lWih [256][128] -> [128][256]
            int i = idx >> 8, r = idx & 255;
            lWihT[i * 256 + r] = lWih[r * 128 + i];
        } else if (idx < 49152) {                // lWhh [256][64] -> [64][256]
            int x2 = idx - 32768; int i = x2 >> 8, r = x2 & 255;
            lWhhT[i * 256 + r] = lWhh[r * 64 + i];
        }
    } else if (b < 15078) {
        // gru/e2b MFMA B-operand packs
        int idx = (b - 14966) * 256 + tid;       // [0, 28672)
        if (idx < 12288) {
            int j = idx & 7, lane = (idx >> 3) & 63, kt = (idx >> 9) & 1, ct = idx >> 10;
            int k = kt * 32 + ((lane >> 4) << 3) + j;
            int n = ct * 16 + (lane & 15);
            float v = gWih[n * 64 + k];
            unsigned short hi = f2bf(v);
            gWihP[idx] = hi;
            gWihP[12288 + idx] = f2bf(v - bf2f(hi));
        } else if (idx < 24576) {
            int i2 = idx - 12288;
            int j = i2 & 7, lane = (i2 >> 3) & 63, kt = (i2 >> 9) & 1, ct = i2 >> 10;
            int k = kt * 32 + ((lane >> 4) << 3) + j;
            int n = ct * 16 + (lane & 15);
            float v = gWhh[n * 64 + k];
            unsigned short hi = f2bf(v);
            gWhhP[i2] = hi;
            gWhhP[12288 + i2] = f2bf(v - bf2f(hi));
        } else {
            int i2 = idx - 24576;                // [0,4096)
            int j = i2 & 7, lane = (i2 >> 3) & 63, kt = (i2 >> 9) & 1, ct = i2 >> 10;
            int k = kt * 32 + ((lane >> 4) << 3) + j;
            int n = ct * 16 + (lane & 15);
            float v = e2b[k * 64 + n];
            unsigned short hi = f2bf(v);
            e2bP[i2] = hi;
            e2bP[4096 + i2] = f2bf(v - bf2f(hi));
        }
    } else if (b < 15137) {
        int n = (b - 15078) * 256 + tid;
        if (n < N_NODES) {
            int bb = batch[n];
            int pb = (n == 0) ? -1 : batch[n - 1];
            for (int g = pb + 1; g <= bb; ++g) gptr[g] = n;
            if (n == N_NODES - 1)
                for (int g = bb + 1; g <= N_GRAPHS; ++g) gptr[g] = N_NODES;
        }
    } else {
        int e = (b - 15137) * 256 + tid;
        if (e < N_EDGES) {
            atomicAdd(&tcnt[src[e] >> 4], 1);
            atomicAdd(&deg[dst[e]], 1.f);
        }
    }
}

// ---------------- fused conv: MFMA phase A + flat message scatter ----------------
// Grid 944x8, nt = bid % 944, ft = bid / 944: ft-siblings share XCD (944 % 8 == 0)
// so h1 rows are fetched into one L2 once. T stride 548 (4*548 % 32 = 16 -> 2-way
// write aliasing, free). Phase B dot uses 4 partial accumulators.
__global__ __launch_bounds__(256, 4)
void conv_kernel(const float* __restrict__ node_h, const float* __restrict__ h1,
                 const unsigned short* __restrict__ Bhi, const unsigned short* __restrict__ Blo,
                 const float* __restrict__ Tb_g,
                 const int* __restrict__ tptr, const int* __restrict__ edge_list,
                 const int* __restrict__ src, const int* __restrict__ dst,
                 float* __restrict__ agg) {
    __shared__ float A_s[16][68];
    __shared__ float Tb_s[16][8];
    __shared__ float T_lds[16 * 548];    // [node]*548 + [fi]*68 + kk
    int bid = blockIdx.x;
    int nt = bid % N_TILES_PAD, ft = bid / N_TILES_PAD;
    int n0 = nt * 16;
    int tid = threadIdx.x;

    {   // stage A-tile (fp32)
        int nn = tid >> 4, d4 = (tid & 15) * 4;
        int n = n0 + nn;
        float4 v = make_float4(0.f, 0.f, 0.f, 0.f);
        if (n < N_NODES) v = *(const float4*)(node_h + (size_t)n * 64 + d4);
        *(float4*)(&A_s[nn][d4]) = v;
    }
    if (tid < 128) {
        int nn = tid >> 3, fi = tid & 7;
        int n = n0 + nn;
        Tb_s[nn][fi] = (n < N_NODES) ? Tb_g[(size_t)n * 64 + ft * 8 + fi] : 0.f;
    }
    __syncthreads();

    int lane = tid & 63, wave = tid >> 6;
    int quad = lane >> 4, m = lane & 15;

    bf16x8 ahi[2], alo[2];
    #pragma unroll
    for (int kt = 0; kt < 2; ++kt) {
        const float* ap = &A_s[m][kt * 32 + quad * 8];
        float4 x0 = *(const float4*)ap;
        float4 x1 = *(const float4*)(ap + 4);
        float av[8] = {x0.x, x0.y, x0.z, x0.w, x1.x, x1.y, x1.z, x1.w};
        #pragma unroll
        for (int j = 0; j < 8; ++j) {
            unsigned short hi = f2bf(av[j]);
            ahi[kt][j] = (short)hi;
            alo[kt][j] = (short)f2bf(av[j] - bf2f(hi));
        }
    }

    // B-frag pointers: ct stride = 1024 shorts, kt stride = 512 shorts
    size_t base0 = ((size_t)((ft * 32 + wave * 8) * 2) * 64 + lane) * 8;
    const unsigned short* ph = Bhi + base0;
    const unsigned short* pl = Blo + base0;
    bf16x8 bh0 = *(const bf16x8*)(ph);
    bf16x8 bh1 = *(const bf16x8*)(ph + 512);
    bf16x8 bl0 = *(const bf16x8*)(pl);
    bf16x8 bl1 = *(const bf16x8*)(pl + 512);

    #pragma unroll 1
    for (int ci = 0; ci < 8; ++ci) {
        bf16x8 ch0 = bh0, ch1 = bh1, cl0 = bl0, cl1 = bl1;
        if (ci < 7) {
            const unsigned short* nh = ph + (ci + 1) * 1024;
            const unsigned short* nl = pl + (ci + 1) * 1024;
            bh0 = *(const bf16x8*)(nh);
            bh1 = *(const bf16x8*)(nh + 512);
            bl0 = *(const bf16x8*)(nl);
            bl1 = *(const bf16x8*)(nl + 512);
        }
        f32x4 accA = {0.f, 0.f, 0.f, 0.f};
        f32x4 accB = {0.f, 0.f, 0.f, 0.f};
        accA = __builtin_amdgcn_mfma_f32_16x16x32_bf16(ahi[0], ch0, accA, 0, 0, 0);
        accB = __builtin_amdgcn_mfma_f32_16x16x32_bf16(ahi[1], ch1, accB, 0, 0, 0);
        accA = __builtin_amdgcn_mfma_f32_16x16x32_bf16(alo[0], ch0, accA, 0, 0, 0);
        accB = __builtin_amdgcn_mfma_f32_16x16x32_bf16(alo[1], ch1, accB, 0, 0, 0);
        accA = __builtin_amdgcn_mfma_f32_16x16x32_bf16(ahi[0], cl0, accA, 0, 0, 0);
        accB = __builtin_amdgcn_mfma_f32_16x16x32_bf16(ahi[1], cl1, accB, 0, 0, 0);
        int c = (wave * 8 + ci) * 16 + m;
        int kk = c >> 3, fi = c & 7;
        #pragma unroll
        for (int r = 0; r < 4; ++r)
            T_lds[(quad * 4 + r) * 548 + fi * 68 + kk] = accA[r] + accB[r];
    }
    __syncthreads();

    int fi = tid & 7, slot = tid >> 3;
    int te0 = tptr[nt], te1 = tptr[nt + 1];
    for (int c = te0 + slot; c < te1; c += 32) {
        int e = edge_list[c];
        int nn = src[e] - n0;
        const float* h1e = h1 + (size_t)e * 64;
        const float* Tr = &T_lds[nn * 548 + fi * 68];
        float p0 = Tb_s[nn][fi], p1 = 0.f, p2 = 0.f, p3 = 0.f;
        #pragma unroll
        for (int k4 = 0; k4 < 64; k4 += 16) {
            float4 ha = *(const float4*)(h1e + k4);
            float4 ta = *(const float4*)(Tr + k4);
            float4 hb = *(const float4*)(h1e + k4 + 4);
            float4 tb = *(const float4*)(Tr + k4 + 4);
            float4 hc = *(const float4*)(h1e + k4 + 8);
            float4 tc = *(const float4*)(Tr + k4 + 8);
            float4 hd = *(const float4*)(h1e + k4 + 12);
            float4 td = *(const float4*)(Tr + k4 + 12);
            p0 += ha.x * ta.x + ha.y * ta.y + ha.z * ta.z + ha.w * ta.w;
            p1 += hb.x * tb.x + hb.y * tb.y + hb.z * tb.z + hb.w * tb.w;
            p2 += hc.x * tc.x + hc.y * tc.y + hc.z * tc.z + hc.w * tc.w;
            p3 += hd.x * td.x + hd.y * td.y + hd.z * td.z + hd.w * td.w;
        }
        float s = (p0 + p1) + (p2 + p3);
        atomicAdd(&agg[(size_t)dst[e] * 64 + ft * 8 + fi], s);
    }
}

// ---------------- GRU as MFMA GEMM: 32 nodes/block (469 blocks, 4 blocks/CU) ------
__global__ __launch_bounds__(256, 4)
void gru_kernel(float* __restrict__ node_h, float* __restrict__ agg,
                const float* __restrict__ deg, const float* __restrict__ conv_b,
                const unsigned short* __restrict__ WihP, const unsigned short* __restrict__ WhhP,
                const float* __restrict__ bih, const float* __restrict__ bhh,
                const unsigned short* __restrict__ e2bP,
                float* __restrict__ Tb_g, int want_tb) {
    __shared__ unsigned short m_bf[2][32][72];
    __shared__ unsigned short h_bf[2][32][72];
    __shared__ unsigned short hn_bf[2][32][72];
    __shared__ float h_s[32][68];
    int n0 = blockIdx.x * 32;
    int tid = threadIdx.x;
    int lane = tid & 63, w = tid >> 6;
    int quad = lane >> 4, m16 = lane & 15;

    for (int i = tid; i < 2048; i += 256) {
        int c = i >> 6, f = i & 63;
        int n = n0 + c;
        float mv = 0.f, hv = 0.f;
        if (n < N_NODES) {
            float dg = fmaxf(deg[n], 1.f);
            mv = fmaxf(agg[(size_t)n * 64 + f] / dg + conv_b[f], 0.f);
            agg[(size_t)n * 64 + f] = 0.f;
            hv = node_h[(size_t)n * 64 + f];
        }
        unsigned short mh = f2bf(mv);
        m_bf[0][c][f] = mh; m_bf[1][c][f] = f2bf(mv - bf2f(mh));
        unsigned short hh = f2bf(hv);
        h_bf[0][c][f] = hh; h_bf[1][c][f] = f2bf(hv - bf2f(hh));
        h_s[c][f] = hv;
    }

    bf16x8 Bi[3][2][2], Bh[3][2][2];
    #pragma unroll
    for (int g = 0; g < 3; ++g)
        #pragma unroll
        for (int kt = 0; kt < 2; ++kt) {
            size_t base = ((size_t)((g * 4 + w) * 2 + kt) * 64 + lane) * 8;
            Bi[g][kt][0] = *(const bf16x8*)(WihP + base);
            Bi[g][kt][1] = *(const bf16x8*)(WihP + 12288 + base);
            Bh[g][kt][0] = *(const bf16x8*)(WhhP + base);
            Bh[g][kt][1] = *(const bf16x8*)(WhhP + 12288 + base);
        }
    int f = w * 16 + m16;
    float br_i = bih[f],       br_h = bhh[f];
    float bz_i = bih[64 + f],  bz_h = bhh[64 + f];
    float bn_i = bih[128 + f], bn_h = bhh[128 + f];
    __syncthreads();

    #pragma unroll 1
    for (int mt = 0; mt < 2; ++mt) {
        bf16x8 Am[2][2], Ah[2][2];
        #pragma unroll
        for (int kt = 0; kt < 2; ++kt) {
            Am[kt][0] = *(const bf16x8*)(&m_bf[0][mt * 16 + m16][kt * 32 + quad * 8]);
            Am[kt][1] = *(const bf16x8*)(&m_bf[1][mt * 16 + m16][kt * 32 + quad * 8]);
            Ah[kt][0] = *(const bf16x8*)(&h_bf[0][mt * 16 + m16][kt * 32 + quad * 8]);
            Ah[kt][1] = *(const bf16x8*)(&h_bf[1][mt * 16 + m16][kt * 32 + quad * 8]);
        }
        f32x4 ai[3], ah[3];
        #pragma unroll
        for (int g = 0; g < 3; ++g) { ai[g] = (f32x4){0.f,0.f,0.f,0.f}; ah[g] = (f32x4){0.f,0.f,0.f,0.f}; }
        #pragma unroll
        for (int g = 0; g < 3; ++g)
            #pragma unroll
            for (int kt = 0; kt < 2; ++kt) {
                ai[g] = __builtin_amdgcn_mfma_f32_16x16x32_bf16(Am[kt][0], Bi[g][kt][0], ai[g], 0, 0, 0);
                ai[g] = __builtin_amdgcn_mfma_f32_16x16x32_bf16(Am[kt][0], Bi[g][kt][1], ai[g], 0, 0, 0);
                ai[g] = __builtin_amdgcn_mfma_f32_16x16x32_bf16(Am[kt][1], Bi[g][kt][0], ai[g], 0, 0, 0);
                ah[g] = __builtin_amdgcn_mfma_f32_16x16x32_bf16(Ah[kt][0], Bh[g][kt][0], ah[g], 0, 0, 0);
                ah[g] = __builtin_amdgcn_mfma_f32_16x16x32_bf16(Ah[kt][0], Bh[g][kt][1], ah[g], 0, 0, 0);
                ah[g] = __builtin_amdgcn_mfma_f32_16x16x32_bf16(Ah[kt][1], Bh[g][kt][0], ah[g], 0, 0, 0);
            }
        #pragma unroll
        for (int r = 0; r < 4; ++r) {
            int node = mt * 16 + quad * 4 + r;
            float rr = sigmoidf_(ai[0][r] + br_i + ah[0][r] + br_h);
            float zz = sigmoidf_(ai[1][r] + bz_i + ah[1][r] + bz_h);
            float n2 = tanhf(ai[2][r] + bn_i + rr * (ah[2][r] + bn_h));
            float hnew = (1.f - zz) * n2 + zz * h_s[node][f];
            int n = n0 + node;
            if (n < N_NODES) node_h[(size_t)n * 64 + f] = hnew;
            unsigned short hh = f2bf(hnew);
            hn_bf[0][node][f] = hh;
            hn_bf[1][node][f] = f2bf(hnew - bf2f(hh));
        }
    }
    if (want_tb) {
        __syncthreads();
        bf16x8 Eb[2][2];
        #pragma unroll
        for (int kt = 0; kt < 2; ++kt) {
            size_t base = ((size_t)((w * 2 + kt) * 64) + lane) * 8;
            Eb[kt][0] = *(const bf16x8*)(e2bP + base);
            Eb[kt][1] = *(const bf16x8*)(e2bP + 4096 + base);
        }
        #pragma unroll 1
        for (int mt = 0; mt < 2; ++mt) {
            bf16x8 A2[2][2];
            #pragma unroll
            for (int kt = 0; kt < 2; ++kt) {
                A2[kt][0] = *(const bf16x8*)(&hn_bf[0][mt * 16 + m16][kt * 32 + quad * 8]);
                A2[kt][1] = *(const bf16x8*)(&hn_bf[1][mt * 16 + m16][kt * 32 + quad * 8]);
            }
            f32x4 acc = {0.f, 0.f, 0.f, 0.f};
            #pragma unroll
            for (int kt = 0; kt < 2; ++kt) {
                acc = __builtin_amdgcn_mfma_f32_16x16x32_bf16(A2[kt][0], Eb[kt][0], acc, 0, 0, 0);
                acc = __builtin_amdgcn_mfma_f32_16x16x32_bf16(A2[kt][0], Eb[kt][1], acc, 0, 0, 0);
                acc = __builtin_amdgcn_mfma_f32_16x16x32_bf16(A2[kt][1], Eb[kt][0], acc, 0, 0, 0);
            }
            #pragma unroll
            for (int r = 0; r < 4; ++r) {
                int n = n0 + mt * 16 + quad * 4 + r;
                if (n < N_NODES) Tb_g[(size_t)n * 64 + f] = acc[r];
            }
        }
    }
}

// ---------------- Set2Set (3 steps) + output MLP, 128 threads (2 waves) per graph ---
__global__ __launch_bounds__(128)
void s2s_kernel(const float* __restrict__ node_h, const int* __restrict__ gptr,
                const float* __restrict__ WihT, const float* __restrict__ WhhT,
                const float* __restrict__ bih, const float* __restrict__ bhh,
                const float* __restrict__ o1W, const float* __restrict__ o1b,
                const float* __restrict__ o2W, const float* __restrict__ o2b,
                float* __restrict__ z) {
    int g = blockIdx.x, tid = threadIdx.x;
    int f = tid & 63, half = tid >> 6;
    __shared__ float qs[128], hs[64], q[64], wts[128], gvs[4][64], racc_s[2][64];
    __shared__ float mred[2], sred[2], ored[2];
    if (half == 0) { qs[f] = 0.f; qs[64 + f] = 0.f; hs[f] = 0.f; }
    float c_t = 0.f;
    int nbeg = gptr[g], nend = gptr[g + 1];
    __syncthreads();
    for (int st = 0; st < 3; ++st) {
        #pragma unroll
        for (int gg = 0; gg < 2; ++gg) {
            int gate = half * 2 + gg;
            int row = gate * 64 + f;
            float s = bih[row] + bhh[row];
            #pragma unroll 8
            for (int i = 0; i < 128; ++i) s += qs[i] * WihT[i * 256 + row];
            #pragma unroll 8
            for (int i = 0; i < 64; ++i) s += hs[i] * WhhT[i * 256 + row];
            gvs[gate][f] = s;
        }
        __syncthreads();
        if (half == 0) {
            float c = sigmoidf_(gvs[1][f]) * c_t + sigmoidf_(gvs[0][f]) * tanhf(gvs[2][f]);
            float hn = sigmoidf_(gvs[3][f]) * tanhf(c);
            c_t = c;
            hs[f] = hn; q[f] = hn;
        }
        __syncthreads();
        float rm = -INFINITY, rs = 0.f, raccl = 0.f;
        for (int base = nbeg; base < nend; base += 128) {
            int n = base + tid;
            float e = -INFINITY;
            if (n < nend) {
                float s = 0.f;
                #pragma unroll 8
                for (int ff = 0; ff < 64; ++ff) s += node_h[(size_t)n * 64 + ff] * q[ff];
                e = s;
            }
            float cm = e;
            #pragma unroll
            for (int o = 32; o > 0; o >>= 1) cm = fmaxf(cm, __shfl_down(cm, o));
            if ((tid & 63) == 0) mred[half] = cm;
            __syncthreads();
            float bm = fmaxf(mred[0], mred[1]);
            float nm = fmaxf(rm, bm);
            float scale = (rm == -INFINITY) ? 0.f : expf(rm - nm);
            float wv = (n < nend) ? expf(e - nm) : 0.f;
            wts[tid] = wv;
            float cs = wv;
            #pragma unroll
            for (int o = 32; o > 0; o >>= 1) cs += __shfl_down(cs, o);
            if ((tid & 63) == 0) sred[half] = cs;
            __syncthreads();
            float bs = sred[0] + sred[1];
            float na = raccl * scale;
            int cnt2 = min(128, nend - base);
            int l0 = half * 64, l1 = min(l0 + 64, cnt2);
            for (int l = l0; l < l1; ++l) na += wts[l] * node_h[(size_t)(base + l) * 64 + f];
            raccl = na;
            rs = rs * scale + bs;
            rm = nm;
            __syncthreads();
        }
        racc_s[half][f] = raccl;
        __syncthreads();
        if (half == 0) {
            float r = (nend > nbeg) ? (racc_s[0][f] + racc_s[1][f]) / rs : 0.f;
            qs[f] = q[f];
            qs[64 + f] = r;
        }
        __syncthreads();
    }
    float sA = o1b[tid];
    #pragma unroll 8
    for (int i = 0; i < 128; ++i) sA += qs[i] * o1W[i * 128 + tid];
    float red = fmaxf(sA, 0.f) * o2W[tid];
    #pragma unroll
    for (int o = 32; o > 0; o >>= 1) red += __shfl_down(red, o);
    if ((tid & 63) == 0) ored[half] = red;
    __syncthreads();
    if (tid == 0) z[g] = ored[0] + ored[1] + o2b[0];
}

extern "C" void kernel_launch(void* const* d_in, const int* in_sizes, int n_in,
                              void* d_out, int out_size, void* d_ws, size_t ws_size,
                              hipStream_t stream) {
    const float* x         = (const float*)d_in[0];
    const float* edge_attr = (const float*)d_in[1];
    const int*   ei        = (const int*)d_in[2];
    const int*   batch     = (const int*)d_in[3];
    const float* in_W      = (const float*)d_in[4];
    const float* in_b      = (const float*)d_in[5];
    const float* e1_W      = (const float*)d_in[6];
    const float* e1_b      = (const float*)d_in[7];
    const float* e2_W      = (const float*)d_in[8];
    const float* e2_b      = (const float*)d_in[9];
    const float* conv_b    = (const float*)d_in[10];
    const float* gWih      = (const float*)d_in[11];
    const float* gWhh      = (const float*)d_in[12];
    const float* gbih      = (const float*)d_in[13];
    const float* gbhh      = (const float*)d_in[14];
    const float* lWih      = (const float*)d_in[15];
    const float* lWhh      = (const float*)d_in[16];
    const float* lbih      = (const float*)d_in[17];
    const float* lbhh      = (const float*)d_in[18];
    const float* o1W       = (const float*)d_in[19];
    const float* o1b       = (const float*)d_in[20];
    const float* o2W       = (const float*)d_in[21];
    const float* o2b       = (const float*)d_in[22];
    const int* src = ei;
    const int* dst = ei + N_EDGES;
    float* z = (float*)d_out;

    char* ws = (char*)d_ws;
    size_t off = 0;
    auto alloc = [&](size_t bytes) {
        void* p = ws + off;
        off = (off + bytes + 255) & ~(size_t)255;
        return p;
    };
    float* node_h   = (float*)alloc((size_t)N_NODES * 64 * 4);
    float* agg      = (float*)alloc((size_t)N_NODES * 64 * 4);
    float* h1       = (float*)alloc((size_t)N_EDGES * 64 * 4);
    unsigned short* Bhi = (unsigned short*)alloc((size_t)262144 * 2);
    unsigned short* Blo = (unsigned short*)alloc((size_t)262144 * 2);
    float* Tb_g     = (float*)alloc((size_t)N_NODES * 64 * 4);
    float* lWihT    = (float*)alloc(128 * 256 * 4);
    float* lWhhT    = (float*)alloc(64 * 256 * 4);
    unsigned short* gWihP = (unsigned short*)alloc(24576 * 2);
    unsigned short* gWhhP = (unsigned short*)alloc(24576 * 2);
    unsigned short* e2bP  = (unsigned short*)alloc(8192 * 2);
    float* deg      = (float*)alloc(N_NODES * 4);       // deg,tcnt adjacent (one memset)
    int*   tcnt     = (int*)alloc((N_TILES + 2) * 4);
    int*   tcursor  = (int*)alloc((N_TILES + 2) * 4);
    int*   tptr     = (int*)alloc((N_TILES_PAD + 2) * 4);
    int*   edge_list= (int*)alloc(N_EDGES * 4);
    int*   gptr     = (int*)alloc((N_GRAPHS + 1) * 4);

    size_t degpad = ((size_t)N_NODES * 4 + 255) & ~(size_t)255;
    hipMemsetAsync(deg, 0, degpad + (N_TILES + 2) * 4, stream);   // deg + tcnt
    hipMemsetAsync(agg, 0, (size_t)N_NODES * 64 * 4, stream);     // once; gru re-zeroes

    prep_kernel<<<15294, 256, 0, stream>>>(x, in_W, in_b, node_h, e2_b, Tb_g,
                                           edge_attr, e1_W, e1_b, h1,
                                           e2_W, Bhi, Blo,
                                           lWih, lWhh, gWih, gWhh,
                                           lWihT, lWhhT, gWihP, gWhhP, e2bP,
                                           batch, gptr, src, dst, tcnt, deg);
    tscan_kernel<<<1, 1024, 0, stream>>>(tcnt, tptr, tcursor);
    fill_kernel<<<(N_EDGES + 255) / 256, 256, 0, stream>>>(src, tcursor, edge_list);

    for (int it = 0; it < 3; ++it) {
        conv_kernel<<<N_TILES_PAD * 8, 256, 0, stream>>>(node_h, h1, Bhi, Blo, Tb_g,
                                                         tptr, edge_list, src, dst, agg);
        gru_kernel<<<469, 256, 0, stream>>>(node_h, agg, deg, conv_b,
                                            gWihP, gWhhP, gbih, gbhh,
                                            e2bP, Tb_g, (it < 2) ? 1 : 0);
    }
    s2s_kernel<<<N_GRAPHS, 128, 0, stream>>>(node_h, gptr, lWihT, lWhhT, lbih, lbhh,
                                             o1W, o1b, o2W, o2b, z);
}

// Round 10
// 432.348 us; speedup vs baseline: 2.3815x; 1.0272x over previous
//
#include <hip/hip_runtime.h>
#include <math.h>

#define N_NODES 15000
#define N_EDGES 40000
#define N_GRAPHS 750
#define N_TILES 938    // ceil(15000/16)
#define N_TILES_PAD 944  // multiple of 8 -> ft-sibling blocks share XCD under round-robin

typedef __attribute__((ext_vector_type(8))) short bf16x8;
typedef __attribute__((ext_vector_type(4))) float f32x4;

__device__ __forceinline__ float sigmoidf_(float x) { return 1.f / (1.f + expf(-x)); }

// round-to-nearest-even fp32 -> bf16 bits
__device__ __forceinline__ unsigned short f2bf(float v) {
    unsigned u = __float_as_uint(v);
    unsigned r = (u + 0x7FFFu + ((u >> 16) & 1u)) >> 16;
    return (unsigned short)r;
}
__device__ __forceinline__ float bf2f(unsigned short b) {
    return __uint_as_float(((unsigned)b) << 16);
}

// ---------------- CSR scan/fill ----------------
__global__ void tscan_kernel(const int* __restrict__ tcnt, int* __restrict__ tptr,
                             int* __restrict__ cursor) {
    __shared__ int buf[1024];
    int t = threadIdx.x;
    int v = (t < N_TILES) ? tcnt[t] : 0;
    buf[t] = v;
    __syncthreads();
    for (int ofs = 1; ofs < 1024; ofs <<= 1) {
        int a = (t >= ofs) ? buf[t - ofs] : 0;
        __syncthreads();
        buf[t] += a;
        __syncthreads();
    }
    int excl = buf[t] - v;
    if (t <= N_TILES_PAD) tptr[t] = excl;   // t>=938 -> excl == total
    if (t < N_TILES) cursor[t] = excl;
}

__global__ void fill_kernel(const int* __restrict__ src, int* __restrict__ cursor,
                            int* __restrict__ edge_list) {
    int e = blockIdx.x * 256 + threadIdx.x;
    if (e >= N_EDGES) return;
    int slot = atomicAdd(&cursor[src[e] >> 4], 1);
    edge_list[slot] = e;
}

// ---------------- fused prep mega-kernel (block-range partitioned) ----------------
// [0,3750): proj. [3750,13750): h1. [13750,14806): conv e2_W+e2_b bf16 pack (33 ct).
// [14806,14998): LSTM transposes. [14998,15094): gru weight packs. [15094,15153): gptr.
// [15153,15310): edge count (tcnt/deg).
__global__ __launch_bounds__(256)
void prep_kernel(const float* __restrict__ x, const float* __restrict__ in_W,
                 const float* __restrict__ in_b, float* __restrict__ node_h,
                 const float* __restrict__ e2b,
                 const float* __restrict__ ea, const float* __restrict__ e1_W,
                 const float* __restrict__ e1_b, float* __restrict__ h1,
                 const float* __restrict__ e2W,
                 unsigned short* __restrict__ Bhi, unsigned short* __restrict__ Blo,
                 const float* __restrict__ lWih, const float* __restrict__ lWhh,
                 const float* __restrict__ gWih, const float* __restrict__ gWhh,
                 float* __restrict__ lWihT, float* __restrict__ lWhhT,
                 unsigned short* __restrict__ gWihP, unsigned short* __restrict__ gWhhP,
                 const int* __restrict__ batch, int* __restrict__ gptr,
                 const int* __restrict__ src, const int* __restrict__ dst,
                 int* __restrict__ tcnt, float* __restrict__ deg) {
    int b = blockIdx.x;
    int tid = threadIdx.x;
    if (b < 3750) {
        __shared__ float xs[4][32];
        int n0 = b * 4;
        if (tid < 128) xs[tid >> 5][tid & 31] = x[n0 * 32 + tid];
        __syncthreads();
        int nn = tid >> 6, f = tid & 63;
        float s = in_b[f];
        #pragma unroll
        for (int i = 0; i < 32; ++i) s += xs[nn][i] * in_W[i * 64 + f];
        node_h[(size_t)(n0 + nn) * 64 + f] = fmaxf(s, 0.f);
    } else if (b < 13750) {
        __shared__ float eas[4][16];
        int e0 = (b - 3750) * 4;
        if (tid < 64) eas[tid >> 4][tid & 15] = ea[e0 * 16 + tid];
        __syncthreads();
        int nn = tid >> 6, f = tid & 63;
        float s = e1_b[f];
        #pragma unroll
        for (int i = 0; i < 16; ++i) s += eas[nn][i] * e1_W[i * 64 + f];
        h1[(size_t)(e0 + nn) * 64 + f] = fmaxf(s, 0.f);
    } else if (b < 14806) {
        // conv B pack, 33 column-tiles per ft (ct 32 = e2_b bias fold):
        // shorts idx = (((ft*33+ct)*2+kt)*64 + lane)*8 + j
        int idx = (b - 13750) * 256 + tid;           // [0, 270336)
        int j = idx & 7, lane = (idx >> 3) & 63, kt = (idx >> 9) & 1;
        int rem = idx >> 10;
        int ct = rem % 33, ft = rem / 33;
        int d = kt * 32 + ((lane >> 4) << 3) + j;
        int m = lane & 15;
        float v;
        if (ct < 32) {
            int c = ct * 16 + m;
            int kk = c >> 3, fi = c & 7;
            v = e2W[(size_t)kk * 4096 + d * 64 + ft * 8 + fi];
        } else {
            v = (m < 8) ? e2b[d * 64 + ft * 8 + m] : 0.f;
        }
        unsigned short hi = f2bf(v);
        Bhi[idx] = hi;
        Blo[idx] = f2bf(v - bf2f(hi));
    } else if (b < 14998) {
        int idx = (b - 14806) * 256 + tid;
        if (idx < 32768) {                       // lWih [256][128] -> [128][256]
            int i = idx >> 8, r = idx & 255;
            lWihT[i * 256 + r] = lWih[r * 128 + i];
        } else if (idx < 49152) {                // lWhh [256][64] -> [64][256]
            int x2 = idx - 32768; int i = x2 >> 8, r = x2 & 255;
            lWhhT[i * 256 + r] = lWhh[r * 64 + i];
        }
    } else if (b < 15094) {
        // gru MFMA B-operand packs
        int idx = (b - 14998) * 256 + tid;       // [0, 24576)
        if (idx < 12288) {
            int j = idx & 7, lane = (idx >> 3) & 63, kt = (idx >> 9) & 1, ct = idx >> 10;
            int k = kt * 32 + ((lane >> 4) << 3) + j;
            int n = ct * 16 + (lane & 15);
            float v = gWih[n * 64 + k];
            unsigned short hi = f2bf(v);
            gWihP[idx] = hi;
            gWihP[12288 + idx] = f2bf(v - bf2f(hi));
        } else {
            int i2 = idx - 12288;
            int j = i2 & 7, lane = (i2 >> 3) & 63, kt = (i2 >> 9) & 1, ct = i2 >> 10;
            int k = kt * 32 + ((lane >> 4) << 3) + j;
            int n = ct * 16 + (lane & 15);
            float v = gWhh[n * 64 + k];
            unsigned short hi = f2bf(v);
            gWhhP[i2] = hi;
            gWhhP[12288 + i2] = f2bf(v - bf2f(hi));
        }
    } else if (b < 15153) {
        int n = (b - 15094) * 256 + tid;
        if (n < N_NODES) {
            int bb = batch[n];
            int pb = (n == 0) ? -1 : batch[n - 1];
            for (int g = pb + 1; g <= bb; ++g) gptr[g] = n;
            if (n == N_NODES - 1)
                for (int g = bb + 1; g <= N_GRAPHS; ++g) gptr[g] = N_NODES;
        }
    } else {
        int e = (b - 15153) * 256 + tid;
        if (e < N_EDGES) {
            atomicAdd(&tcnt[src[e] >> 4], 1);
            atomicAdd(&deg[dst[e]], 1.f);
        }
    }
}

// ---------------- fused conv: MFMA phase A (Tb folded) + dual-edge scatter ----------
// Grid 944x8, nt = bid % 944 (ft-siblings share XCD). Phase A covers 33 column
// tiles (ct 32 = bias -> T_lds[..][64]); wave w does ct = w, w+4, ... Phase B
// processes 2 edges per slot concurrently (independent load/FMA chains).
__global__ __launch_bounds__(256, 4)
void conv_kernel(const float* __restrict__ node_h, const float* __restrict__ h1,
                 const unsigned short* __restrict__ Bhi, const unsigned short* __restrict__ Blo,
                 const int* __restrict__ tptr, const int* __restrict__ edge_list,
                 const int* __restrict__ src, const int* __restrict__ dst,
                 float* __restrict__ agg) {
    __shared__ float A_s[16][68];
    __shared__ float T_lds[16 * 548];    // [node]*548 + [fi]*68 + kk ; kk 0..63 + 64=Tb
    int bid = blockIdx.x;
    int nt = bid % N_TILES_PAD, ft = bid / N_TILES_PAD;
    int n0 = nt * 16;
    int tid = threadIdx.x;

    {   // stage A-tile (fp32)
        int nn = tid >> 4, d4 = (tid & 15) * 4;
        int n = n0 + nn;
        float4 v = make_float4(0.f, 0.f, 0.f, 0.f);
        if (n < N_NODES) v = *(const float4*)(node_h + (size_t)n * 64 + d4);
        *(float4*)(&A_s[nn][d4]) = v;
    }
    __syncthreads();

    int lane = tid & 63, wave = tid >> 6;
    int quad = lane >> 4, m = lane & 15;

    bf16x8 ahi[2], alo[2];
    #pragma unroll
    for (int kt = 0; kt < 2; ++kt) {
        const float* ap = &A_s[m][kt * 32 + quad * 8];
        float4 x0 = *(const float4*)ap;
        float4 x1 = *(const float4*)(ap + 4);
        float av[8] = {x0.x, x0.y, x0.z, x0.w, x1.x, x1.y, x1.z, x1.w};
        #pragma unroll
        for (int j = 0; j < 8; ++j) {
            unsigned short hi = f2bf(av[j]);
            ahi[kt][j] = (short)hi;
            alo[kt][j] = (short)f2bf(av[j] - bf2f(hi));
        }
    }

    // B-frag pointers: ct stride 1024 shorts, kt +512; wave w: ct = w, w+4, ...
    size_t base0 = (size_t)(ft * 33 + wave) * 1024 + lane * 8;
    const unsigned short* ph = Bhi + base0;
    const unsigned short* pl = Blo + base0;
    bf16x8 bh0 = *(const bf16x8*)(ph);
    bf16x8 bh1 = *(const bf16x8*)(ph + 512);
    bf16x8 bl0 = *(const bf16x8*)(pl);
    bf16x8 bl1 = *(const bf16x8*)(pl + 512);

    int nct = (wave == 0) ? 9 : 8;
    #pragma unroll 1
    for (int ci = 0; ci < nct; ++ci) {
        bf16x8 ch0 = bh0, ch1 = bh1, cl0 = bl0, cl1 = bl1;
        if (ci + 1 < nct) {
            const unsigned short* nh = ph + (size_t)(ci + 1) * 4096;
            const unsigned short* nl = pl + (size_t)(ci + 1) * 4096;
            bh0 = *(const bf16x8*)(nh);
            bh1 = *(const bf16x8*)(nh + 512);
            bl0 = *(const bf16x8*)(nl);
            bl1 = *(const bf16x8*)(nl + 512);
        }
        f32x4 accA = {0.f, 0.f, 0.f, 0.f};
        f32x4 accB = {0.f, 0.f, 0.f, 0.f};
        accA = __builtin_amdgcn_mfma_f32_16x16x32_bf16(ahi[0], ch0, accA, 0, 0, 0);
        accB = __builtin_amdgcn_mfma_f32_16x16x32_bf16(ahi[1], ch1, accB, 0, 0, 0);
        accA = __builtin_amdgcn_mfma_f32_16x16x32_bf16(alo[0], ch0, accA, 0, 0, 0);
        accB = __builtin_amdgcn_mfma_f32_16x16x32_bf16(alo[1], ch1, accB, 0, 0, 0);
        accA = __builtin_amdgcn_mfma_f32_16x16x32_bf16(ahi[0], cl0, accA, 0, 0, 0);
        accB = __builtin_amdgcn_mfma_f32_16x16x32_bf16(ahi[1], cl1, accB, 0, 0, 0);
        int ct = wave + ci * 4;
        int c = ct * 16 + m;
        int kk = c >> 3, fi = c & 7;   // ct=32: kk=64/65 (65 = harmless pad)
        #pragma unroll
        for (int r = 0; r < 4; ++r)
            T_lds[(quad * 4 + r) * 548 + fi * 68 + kk] = accA[r] + accB[r];
    }
    __syncthreads();

    // Phase B: dual-edge per slot, independent chains
    int fi = tid & 7, slot = tid >> 3;
    int te0 = tptr[nt], te1 = tptr[nt + 1];
    for (int c = te0 + slot; c < te1; c += 64) {
        int c1 = c + 32;
        bool h2 = (c1 < te1);
        int e0 = edge_list[c];
        int e1 = h2 ? edge_list[c1] : e0;
        int nn0 = src[e0] - n0, nn1 = src[e1] - n0;
        const float* h0p = h1 + (size_t)e0 * 64;
        const float* h1p = h1 + (size_t)e1 * 64;
        const float* T0 = &T_lds[nn0 * 548 + fi * 68];
        const float* T1 = &T_lds[nn1 * 548 + fi * 68];
        float p00 = T0[64], p01 = 0.f;   // Tb slot
        float p10 = T1[64], p11 = 0.f;
        #pragma unroll
        for (int k4 = 0; k4 < 64; k4 += 8) {
            float4 ha = *(const float4*)(h0p + k4);
            float4 ta = *(const float4*)(T0 + k4);
            float4 hb = *(const float4*)(h0p + k4 + 4);
            float4 tb = *(const float4*)(T0 + k4 + 4);
            float4 hc = *(const float4*)(h1p + k4);
            float4 tc = *(const float4*)(T1 + k4);
            float4 hd = *(const float4*)(h1p + k4 + 4);
            float4 td = *(const float4*)(T1 + k4 + 4);
            p00 += ha.x * ta.x + ha.y * ta.y + ha.z * ta.z + ha.w * ta.w;
            p01 += hb.x * tb.x + hb.y * tb.y + hb.z * tb.z + hb.w * tb.w;
            p10 += hc.x * tc.x + hc.y * tc.y + hc.z * tc.z + hc.w * tc.w;
            p11 += hd.x * td.x + hd.y * td.y + hd.z * td.z + hd.w * td.w;
        }
        atomicAdd(&agg[(size_t)dst[e0] * 64 + ft * 8 + fi], p00 + p01);
        if (h2) atomicAdd(&agg[(size_t)dst[e1] * 64 + ft * 8 + fi], p10 + p11);
    }
}

// ---------------- GRU as MFMA GEMM: 32 nodes/block (469 blocks) ----------------
__global__ __launch_bounds__(256, 4)
void gru_kernel(float* __restrict__ node_h, float* __restrict__ agg,
                const float* __restrict__ deg, const float* __restrict__ conv_b,
                const unsigned short* __restrict__ WihP, const unsigned short* __restrict__ WhhP,
                const float* __restrict__ bih, const float* __restrict__ bhh) {
    __shared__ unsigned short m_bf[2][32][72];
    __shared__ unsigned short h_bf[2][32][72];
    __shared__ float h_s[32][68];
    int n0 = blockIdx.x * 32;
    int tid = threadIdx.x;
    int lane = tid & 63, w = tid >> 6;
    int quad = lane >> 4, m16 = lane & 15;

    for (int i = tid; i < 2048; i += 256) {
        int c = i >> 6, f = i & 63;
        int n = n0 + c;
        float mv = 0.f, hv = 0.f;
        if (n < N_NODES) {
            float dg = fmaxf(deg[n], 1.f);
            mv = fmaxf(agg[(size_t)n * 64 + f] / dg + conv_b[f], 0.f);
            agg[(size_t)n * 64 + f] = 0.f;
            hv = node_h[(size_t)n * 64 + f];
        }
        unsigned short mh = f2bf(mv);
        m_bf[0][c][f] = mh; m_bf[1][c][f] = f2bf(mv - bf2f(mh));
        unsigned short hh = f2bf(hv);
        h_bf[0][c][f] = hh; h_bf[1][c][f] = f2bf(hv - bf2f(hh));
        h_s[c][f] = hv;
    }

    bf16x8 Bi[3][2][2], Bh[3][2][2];
    #pragma unroll
    for (int g = 0; g < 3; ++g)
        #pragma unroll
        for (int kt = 0; kt < 2; ++kt) {
            size_t base = ((size_t)((g * 4 + w) * 2 + kt) * 64 + lane) * 8;
            Bi[g][kt][0] = *(const bf16x8*)(WihP + base);
            Bi[g][kt][1] = *(const bf16x8*)(WihP + 12288 + base);
            Bh[g][kt][0] = *(const bf16x8*)(WhhP + base);
            Bh[g][kt][1] = *(const bf16x8*)(WhhP + 12288 + base);
        }
    int f = w * 16 + m16;
    float br_i = bih[f],       br_h = bhh[f];
    float bz_i = bih[64 + f],  bz_h = bhh[64 + f];
    float bn_i = bih[128 + f], bn_h = bhh[128 + f];
    __syncthreads();

    #pragma unroll 1
    for (int mt = 0; mt < 2; ++mt) {
        bf16x8 Am[2][2], Ah[2][2];
        #pragma unroll
        for (int kt = 0; kt < 2; ++kt) {
            Am[kt][0] = *(const bf16x8*)(&m_bf[0][mt * 16 + m16][kt * 32 + quad * 8]);
            Am[kt][1] = *(const bf16x8*)(&m_bf[1][mt * 16 + m16][kt * 32 + quad * 8]);
            Ah[kt][0] = *(const bf16x8*)(&h_bf[0][mt * 16 + m16][kt * 32 + quad * 8]);
            Ah[kt][1] = *(const bf16x8*)(&h_bf[1][mt * 16 + m16][kt * 32 + quad * 8]);
        }
        f32x4 ai[3], ah[3];
        #pragma unroll
        for (int g = 0; g < 3; ++g) { ai[g] = (f32x4){0.f,0.f,0.f,0.f}; ah[g] = (f32x4){0.f,0.f,0.f,0.f}; }
        #pragma unroll
        for (int g = 0; g < 3; ++g)
            #pragma unroll
            for (int kt = 0; kt < 2; ++kt) {
                ai[g] = __builtin_amdgcn_mfma_f32_16x16x32_bf16(Am[kt][0], Bi[g][kt][0], ai[g], 0, 0, 0);
                ai[g] = __builtin_amdgcn_mfma_f32_16x16x32_bf16(Am[kt][0], Bi[g][kt][1], ai[g], 0, 0, 0);
                ai[g] = __builtin_amdgcn_mfma_f32_16x16x32_bf16(Am[kt][1], Bi[g][kt][0], ai[g], 0, 0, 0);
                ah[g] = __builtin_amdgcn_mfma_f32_16x16x32_bf16(Ah[kt][0], Bh[g][kt][0], ah[g], 0, 0, 0);
                ah[g] = __builtin_amdgcn_mfma_f32_16x16x32_bf16(Ah[kt][0], Bh[g][kt][1], ah[g], 0, 0, 0);
                ah[g] = __builtin_amdgcn_mfma_f32_16x16x32_bf16(Ah[kt][1], Bh[g][kt][0], ah[g], 0, 0, 0);
            }
        #pragma unroll
        for (int r = 0; r < 4; ++r) {
            int node = mt * 16 + quad * 4 + r;
            float rr = sigmoidf_(ai[0][r] + br_i + ah[0][r] + br_h);
            float zz = sigmoidf_(ai[1][r] + bz_i + ah[1][r] + bz_h);
            float n2 = tanhf(ai[2][r] + bn_i + rr * (ah[2][r] + bn_h));
            float hnew = (1.f - zz) * n2 + zz * h_s[node][f];
            int n = n0 + node;
            if (n < N_NODES) node_h[(size_t)n * 64 + f] = hnew;
        }
    }
}

// ---------------- Set2Set (3 steps) + output MLP, 128 threads (2 waves) per graph ---
__global__ __launch_bounds__(128)
void s2s_kernel(const float* __restrict__ node_h, const int* __restrict__ gptr,
                const float* __restrict__ WihT, const float* __restrict__ WhhT,
                const float* __restrict__ bih, const float* __restrict__ bhh,
                const float* __restrict__ o1W, const float* __restrict__ o1b,
                const float* __restrict__ o2W, const float* __restrict__ o2b,
                float* __restrict__ z) {
    int g = blockIdx.x, tid = threadIdx.x;
    int f = tid & 63, half = tid >> 6;
    __shared__ float qs[128], hs[64], q[64], wts[128], gvs[4][64], racc_s[2][64];
    __shared__ float mred[2], sred[2], ored[2];
    if (half == 0) { qs[f] = 0.f; qs[64 + f] = 0.f; hs[f] = 0.f; }
    float c_t = 0.f;
    int nbeg = gptr[g], nend = gptr[g + 1];
    __syncthreads();
    for (int st = 0; st < 3; ++st) {
        #pragma unroll
        for (int gg = 0; gg < 2; ++gg) {
            int gate = half * 2 + gg;
            int row = gate * 64 + f;
            float s = bih[row] + bhh[row];
            #pragma unroll 8
            for (int i = 0; i < 128; ++i) s += qs[i] * WihT[i * 256 + row];
            #pragma unroll 8
            for (int i = 0; i < 64; ++i) s += hs[i] * WhhT[i * 256 + row];
            gvs[gate][f] = s;
        }
        __syncthreads();
        if (half == 0) {
            float c = sigmoidf_(gvs[1][f]) * c_t + sigmoidf_(gvs[0][f]) * tanhf(gvs[2][f]);
            float hn = sigmoidf_(gvs[3][f]) * tanhf(c);
            c_t = c;
            hs[f] = hn; q[f] = hn;
        }
        __syncthreads();
        float rm = -INFINITY, rs = 0.f, raccl = 0.f;
        for (int base = nbeg; base < nend; base += 128) {
            int n = base + tid;
            float e = -INFINITY;
            if (n < nend) {
                float s = 0.f;
                #pragma unroll 8
                for (int ff = 0; ff < 64; ++ff) s += node_h[(size_t)n * 64 + ff] * q[ff];
                e = s;
            }
            float cm = e;
            #pragma unroll
            for (int o = 32; o > 0; o >>= 1) cm = fmaxf(cm, __shfl_down(cm, o));
            if ((tid & 63) == 0) mred[half] = cm;
            __syncthreads();
            float bm = fmaxf(mred[0], mred[1]);
            float nm = fmaxf(rm, bm);
            float scale = (rm == -INFINITY) ? 0.f : expf(rm - nm);
            float wv = (n < nend) ? expf(e - nm) : 0.f;
            wts[tid] = wv;
            float cs = wv;
            #pragma unroll
            for (int o = 32; o > 0; o >>= 1) cs += __shfl_down(cs, o);
            if ((tid & 63) == 0) sred[half] = cs;
            __syncthreads();
            float bs = sred[0] + sred[1];
            float na = raccl * scale;
            int cnt2 = min(128, nend - base);
            int l0 = half * 64, l1 = min(l0 + 64, cnt2);
            for (int l = l0; l < l1; ++l) na += wts[l] * node_h[(size_t)(base + l) * 64 + f];
            raccl = na;
            rs = rs * scale + bs;
            rm = nm;
            __syncthreads();
        }
        racc_s[half][f] = raccl;
        __syncthreads();
        if (half == 0) {
            float r = (nend > nbeg) ? (racc_s[0][f] + racc_s[1][f]) / rs : 0.f;
            qs[f] = q[f];
            qs[64 + f] = r;
        }
        __syncthreads();
    }
    float sA = o1b[tid];
    #pragma unroll 8
    for (int i = 0; i < 128; ++i) sA += qs[i] * o1W[i * 128 + tid];
    float red = fmaxf(sA, 0.f) * o2W[tid];
    #pragma unroll
    for (int o = 32; o > 0; o >>= 1) red += __shfl_down(red, o);
    if ((tid & 63) == 0) ored[half] = red;
    __syncthreads();
    if (tid == 0) z[g] = ored[0] + ored[1] + o2b[0];
}

extern "C" void kernel_launch(void* const* d_in, const int* in_sizes, int n_in,
                              void* d_out, int out_size, void* d_ws, size_t ws_size,
                              hipStream_t stream) {
    const float* x         = (const float*)d_in[0];
    const float* edge_attr = (const float*)d_in[1];
    const int*   ei        = (const int*)d_in[2];
    const int*   batch     = (const int*)d_in[3];
    const float* in_W      = (const float*)d_in[4];
    const float* in_b      = (const float*)d_in[5];
    const float* e1_W      = (const float*)d_in[6];
    const float* e1_b      = (const float*)d_in[7];
    const float* e2_W      = (const float*)d_in[8];
    const float* e2_b      = (const float*)d_in[9];
    const float* conv_b    = (const float*)d_in[10];
    const float* gWih      = (const float*)d_in[11];
    const float* gWhh      = (const float*)d_in[12];
    const float* gbih      = (const float*)d_in[13];
    const float* gbhh      = (const float*)d_in[14];
    const float* lWih      = (const float*)d_in[15];
    const float* lWhh      = (const float*)d_in[16];
    const float* lbih      = (const float*)d_in[17];
    const float* lbhh      = (const float*)d_in[18];
    const float* o1W       = (const float*)d_in[19];
    const float* o1b       = (const float*)d_in[20];
    const float* o2W       = (const float*)d_in[21];
    const float* o2b       = (const float*)d_in[22];
    const int* src = ei;
    const int* dst = ei + N_EDGES;
    float* z = (float*)d_out;

    char* ws = (char*)d_ws;
    size_t off = 0;
    auto alloc = [&](size_t bytes) {
        void* p = ws + off;
        off = (off + bytes + 255) & ~(size_t)255;
        return p;
    };
    float* node_h   = (float*)alloc((size_t)N_NODES * 64 * 4);
    float* agg      = (float*)alloc((size_t)N_NODES * 64 * 4);
    float* h1       = (float*)alloc((size_t)N_EDGES * 64 * 4);
    unsigned short* Bhi = (unsigned short*)alloc((size_t)270336 * 2);
    unsigned short* Blo = (unsigned short*)alloc((size_t)270336 * 2);
    float* lWihT    = (float*)alloc(128 * 256 * 4);
    float* lWhhT    = (float*)alloc(64 * 256 * 4);
    unsigned short* gWihP = (unsigned short*)alloc(24576 * 2);
    unsigned short* gWhhP = (unsigned short*)alloc(24576 * 2);
    float* deg      = (float*)alloc(N_NODES * 4);       // deg,tcnt adjacent (one memset)
    int*   tcnt     = (int*)alloc((N_TILES + 2) * 4);
    int*   tcursor  = (int*)alloc((N_TILES + 2) * 4);
    int*   tptr     = (int*)alloc((N_TILES_PAD + 2) * 4);
    int*   edge_list= (int*)alloc(N_EDGES * 4);
    int*   gptr     = (int*)alloc((N_GRAPHS + 1) * 4);

    size_t degpad = ((size_t)N_NODES * 4 + 255) & ~(size_t)255;
    hipMemsetAsync(deg, 0, degpad + (N_TILES + 2) * 4, stream);   // deg + tcnt
    hipMemsetAsync(agg, 0, (size_t)N_NODES * 64 * 4, stream);     // once; gru re-zeroes

    prep_kernel<<<15310, 256, 0, stream>>>(x, in_W, in_b, node_h, e2_b,
                                           edge_attr, e1_W, e1_b, h1,
                                           e2_W, Bhi, Blo,
                                           lWih, lWhh, gWih, gWhh,
                                           lWihT, lWhhT, gWihP, gWhhP,
                                           batch, gptr, src, dst, tcnt, deg);
    tscan_kernel<<<1, 1024, 0, stream>>>(tcnt, tptr, tcursor);
    fill_kernel<<<(N_EDGES + 255) / 256, 256, 0, stream>>>(src, tcursor, edge_list);

    for (int it = 0; it < 3; ++it) {
        conv_kernel<<<N_TILES_PAD * 8, 256, 0, stream>>>(node_h, h1, Bhi, Blo,
                                                         tptr, edge_list, src, dst, agg);
        gru_kernel<<<469, 256, 0, stream>>>(node_h, agg, deg, conv_b,
                                            gWihP, gWhhP, gbih, gbhh);
    }
    s2s_kernel<<<N_GRAPHS, 128, 0, stream>>>(node_h, gptr, lWihT, lWhhT, lbih, lbhh,
                                             o1W, o1b, o2W, o2b, z);
}